// Round 15
// baseline (318.663 us; speedup 1.0000x reference)
//
#include <hip/hip_runtime.h>
#include <hip/hip_bf16.h>

#define NN 65536
#define NE 1048576
#define EW 4096   // persistent waves in k_edge (1024 blocks x 4 waves = 4 blk/CU)

typedef __attribute__((ext_vector_type(8))) short short8;
typedef __attribute__((ext_vector_type(8))) unsigned short bf16x8;
typedef __attribute__((ext_vector_type(4))) unsigned short bf16x4;
typedef __attribute__((ext_vector_type(4))) float f32x4;
typedef __attribute__((ext_vector_type(4))) unsigned int u32x4;
typedef __attribute__((ext_vector_type(2))) unsigned int u32x2;
typedef __attribute__((ext_vector_type(4))) int i32x4;

__device__ __forceinline__ float lrelu(float x) { return fmaxf(x, 0.01f * x); }
__device__ __forceinline__ float frelu(float x) { return fmaxf(x, 0.f); }
__device__ __forceinline__ short f2bf(float f) {
    __hip_bfloat16 h = __float2bfloat16(f);
    return *reinterpret_cast<short*>(&h);
}
__device__ __forceinline__ float bf2f(unsigned short s) {
    return __uint_as_float(((unsigned)s) << 16);
}
// single-instruction packed f32x2 -> bf16x2 (RNE), lo in low half
__device__ __forceinline__ unsigned pk2(float lo, float hi) {
    unsigned r;
    asm("v_cvt_pk_bf16_f32 %0, %1, %2" : "=v"(r) : "v"(lo), "v"(hi));
    return r;
}
__device__ __forceinline__ void st4(unsigned short* p, f32x4 v) {
    u32x2 w; w[0] = pk2(v[0], v[1]); w[1] = pk2(v[2], v[3]);
    *(u32x2*)p = w;
}

// ---- pack MFMA A-frags: 0=P2 1=A1 2=A2(x log2e) 3=Wout_hi 4=Wout_lo 5=Win 6=Wlin
//      7=Wda(=Wdst@A1) 8=Wsa(=Wsrc@A1); blocks >=18 zero deg ----
__global__ void k_pack(const float* __restrict__ P2, const float* __restrict__ A1,
                       const float* __restrict__ A2, const float* __restrict__ Wout,
                       const float* __restrict__ Win, const float* __restrict__ Wlin,
                       const float* __restrict__ Wdst, const float* __restrict__ Wsrc,
                       short* __restrict__ Apack, int* __restrict__ deg) {
    if (blockIdx.x >= 18) {            // deg zeroing: 64 blocks x 256 x 4 ints
        int i = (blockIdx.x - 18) * 1024 + threadIdx.x * 4;
        *(i32x4*)(deg + i) = (i32x4)0;
        return;
    }
    int idx = blockIdx.x * 256 + threadIdx.x;   // fid*512 + (rb*2+s)*64 + l
    if (idx >= 9 * 512) return;
    int l = idx & 63, s = (idx >> 6) & 1, rb = (idx >> 7) & 3, fid = idx >> 9;
    const float* Wt[7] = {P2, A1, A2, Wout, Wout, Win, Wlin};
    bool lo = (fid == 4);
#pragma unroll
    for (int b = 0; b < 8; ++b) {
        int in = 32 * s + 8 * (l >> 4) + b;
        int out = 16 * rb + (l & 15);
        float w;
        if (fid >= 7) {
            const float* Wsel = (fid == 7) ? Wdst : Wsrc;
            float acc = 0.f;
            for (int k = 0; k < 64; ++k) acc += Wsel[in * 64 + k] * A1[k * 64 + out];
            w = acc;
        } else {
            w = Wt[fid][in * 64 + out];
            if (fid == 2) w *= 1.44269504088896f;   // fold exp->exp2
        }
        short hi = f2bf(w);
        Apack[idx * 8 + b] = lo ? f2bf(w - bf2f((unsigned short)hi)) : hi;
    }
}

// packed-bf16 transpose via bpermute (used by k_front node blocks only)
__device__ __forceinline__ short8 mkfrag(u32x4 c, int la4, int lb4, bool hi) {
    u32x4 r;
    unsigned a0 = (unsigned)__builtin_amdgcn_ds_bpermute(la4, (int)c[0]);
    unsigned a1 = (unsigned)__builtin_amdgcn_ds_bpermute(la4, (int)c[1]);
    unsigned b0 = (unsigned)__builtin_amdgcn_ds_bpermute(la4, (int)c[2]);
    unsigned b1 = (unsigned)__builtin_amdgcn_ds_bpermute(la4, (int)c[3]);
    r[0] = hi ? b0 : a0; r[1] = hi ? b1 : a1;
    a0 = (unsigned)__builtin_amdgcn_ds_bpermute(lb4, (int)c[0]);
    a1 = (unsigned)__builtin_amdgcn_ds_bpermute(lb4, (int)c[1]);
    b0 = (unsigned)__builtin_amdgcn_ds_bpermute(lb4, (int)c[2]);
    b1 = (unsigned)__builtin_amdgcn_ds_bpermute(lb4, (int)c[3]);
    r[2] = hi ? b0 : a0; r[3] = hi ? b1 : a1;
    return __builtin_bit_cast(short8, r);
}

#define MFMA(a, b, c) __builtin_amdgcn_mfma_f32_16x16x32_bf16(a, b, c, 0, 0, 0)

// ---- fused front: node MFMA (1024) || hist+slot-record (4096) || srtj zero (2048)
// gsv row (192 bf16): [0..63]=q ; [64+32rb+8g+0..3]=s ; [64+32rb+8g+4..7]=v
__global__ void __launch_bounds__(256) k_front(
    const float* __restrict__ x, const float* __restrict__ pos,
    const short* __restrict__ Apack,
    const float* __restrict__ bin, const float* __restrict__ a1,
    const float* __restrict__ P1, const float* __restrict__ p1,
    const int* __restrict__ ei, int* __restrict__ deg, int* __restrict__ eslot,
    int* __restrict__ srtj,
    unsigned short* __restrict__ gsv, unsigned short* __restrict__ nad) {
    if (blockIdx.x >= 5120) {          // srtj zeroing: 2048 blocks x 256 x 4 ints
        int i = (blockIdx.x - 5120) * 1024 + threadIdx.x * 4;
        *(i32x4*)(srtj + i) = (i32x4)0;
        return;
    }
    if (blockIdx.x >= 1024) {          // histogram + slot record
        int e = (blockIdx.x - 1024) * 256 + threadIdx.x;
        eslot[e] = atomicAdd(&deg[ei[NE + e]], 1);
        return;
    }
    __shared__ short AW2[4 * 4096];   // fids 5..8: Win, Wlin, Wda, Wsa
    __shared__ float cb[384];         // [0]bin [64]a1 [128]p1 [192..384]P1
    {
        const int* gA = (const int*)(Apack + 5 * 4096);
        int* sA = (int*)AW2;
        for (int i = threadIdx.x; i < 8192; i += 256) sA[i] = gA[i];
        if (threadIdx.x < 64) {
            cb[threadIdx.x] = bin[threadIdx.x];
            cb[64 + threadIdx.x] = a1[threadIdx.x];
            cb[128 + threadIdx.x] = p1[threadIdx.x];
        }
        if (threadIdx.x < 192) cb[192 + threadIdx.x] = P1[threadIdx.x];
    }
    __syncthreads();
    int l = threadIdx.x & 63, g = l >> 4, e = l & 15;
    int la4 = (32 * (g & 1) + e) * 4, lb4 = la4 + 64;
    bool hi = (g >= 2);
#define AF2(f, rb, s) (*(const short8*)(AW2 + ((((f) * 4 + (rb)) * 2 + (s)) * 64 + l) * 8))
    {
        int tile = blockIdx.x * 4 + (threadIdx.x >> 6);   // 0..4095, 1 tile/wave
        int n = tile * 16 + e;
        float p0 = pos[n * 3 + 0], p1v = pos[n * 3 + 1], p2v = pos[n * 3 + 2];
        const float* xr = x + (size_t)n * 64 + 8 * g;
        f32x4 x00 = *(const f32x4*)(xr), x01 = *(const f32x4*)(xr + 4);
        f32x4 x10 = *(const f32x4*)(xr + 32), x11 = *(const f32x4*)(xr + 36);
        short8 xh[2], xl[2];
#pragma unroll
        for (int b = 0; b < 4; ++b) {
            float f;
            f = x00[b]; xh[0][b] = f2bf(f);     xl[0][b] = f2bf(f - bf2f((unsigned short)xh[0][b]));
            f = x01[b]; xh[0][b + 4] = f2bf(f); xl[0][b + 4] = f2bf(f - bf2f((unsigned short)xh[0][b + 4]));
            f = x10[b]; xh[1][b] = f2bf(f);     xl[1][b] = f2bf(f - bf2f((unsigned short)xh[1][b]));
            f = x11[b]; xh[1][b + 4] = f2bf(f); xl[1][b + 4] = f2bf(f - bf2f((unsigned short)xh[1][b + 4]));
        }
        // h = relu(Win^T x + bin)
        f32x4 acc[4];
#pragma unroll
        for (int rb = 0; rb < 4; ++rb) acc[rb] = *(const f32x4*)(cb + 16 * rb + 4 * g);
#pragma unroll
        for (int rb = 0; rb < 4; ++rb) {
            acc[rb] = MFMA(AF2(0, rb, 0), xh[0], acc[rb]);
            acc[rb] = MFMA(AF2(0, rb, 1), xh[1], acc[rb]);
            acc[rb] = MFMA(AF2(0, rb, 0), xl[0], acc[rb]);
            acc[rb] = MFMA(AF2(0, rb, 1), xl[1], acc[rb]);
        }
        f32x4 hv[4], res[4];
#pragma unroll
        for (int rb = 0; rb < 4; ++rb)
#pragma unroll
            for (int c = 0; c < 4; ++c) {
                float f = frelu(acc[rb][c]);
                hv[rb][c] = f;
                res[rb][c] = f - bf2f((unsigned short)f2bf(f));
            }
        u32x4 HhA, HhB, HlA, HlB;
        HhA[0] = pk2(hv[0][0], hv[0][1]); HhA[1] = pk2(hv[0][2], hv[0][3]);
        HhA[2] = pk2(hv[1][0], hv[1][1]); HhA[3] = pk2(hv[1][2], hv[1][3]);
        HhB[0] = pk2(hv[2][0], hv[2][1]); HhB[1] = pk2(hv[2][2], hv[2][3]);
        HhB[2] = pk2(hv[3][0], hv[3][1]); HhB[3] = pk2(hv[3][2], hv[3][3]);
        HlA[0] = pk2(res[0][0], res[0][1]); HlA[1] = pk2(res[0][2], res[0][3]);
        HlA[2] = pk2(res[1][0], res[1][1]); HlA[3] = pk2(res[1][2], res[1][3]);
        HlB[0] = pk2(res[2][0], res[2][1]); HlB[1] = pk2(res[2][2], res[2][3]);
        HlB[2] = pk2(res[3][0], res[3][1]); HlB[3] = pk2(res[3][2], res[3][3]);
        short8 bhh0 = mkfrag(HhA, la4, lb4, hi), bhh1 = mkfrag(HhB, la4, lb4, hi);
        short8 bhl0 = mkfrag(HlA, la4, lb4, hi), bhl1 = mkfrag(HlB, la4, lb4, hi);

        unsigned short* gr = gsv + (size_t)n * 192;
        unsigned short* nr = nad + (size_t)n * 128;
        f32x4 vres[4];
#pragma unroll
        for (int rb = 0; rb < 4; ++rb) {   // v = h @ Wlin (regs)
            f32x4 a = (f32x4)0.f;
            a = MFMA(AF2(1, rb, 0), bhh0, a);
            a = MFMA(AF2(1, rb, 1), bhh1, a);
            a = MFMA(AF2(1, rb, 0), bhl0, a);
            a = MFMA(AF2(1, rb, 1), bhl1, a);
            vres[rb] = a;
        }
#pragma unroll
        for (int rb = 0; rb < 4; ++rb) {   // s = h @ Wsa; write combined {s,v} b128
            f32x4 a = (f32x4)0.f;
            a = MFMA(AF2(3, rb, 0), bhh0, a);
            a = MFMA(AF2(3, rb, 1), bhh1, a);
            a = MFMA(AF2(3, rb, 0), bhl0, a);
            a = MFMA(AF2(3, rb, 1), bhl1, a);
            u32x4 wv4;
            wv4[0] = pk2(a[0], a[1]); wv4[1] = pk2(a[2], a[3]);
            wv4[2] = pk2(vres[rb][0], vres[rb][1]); wv4[3] = pk2(vres[rb][2], vres[rb][3]);
            *(u32x4*)(gr + 64 + 32 * rb + 8 * g) = wv4;
        }
#pragma unroll
        for (int rb = 0; rb < 4; ++rb) {   // ad = h @ Wda + a1
            f32x4 a = *(const f32x4*)(cb + 64 + 16 * rb + 4 * g);
            a = MFMA(AF2(2, rb, 0), bhh0, a);
            a = MFMA(AF2(2, rb, 1), bhh1, a);
            a = MFMA(AF2(2, rb, 0), bhl0, a);
            a = MFMA(AF2(2, rb, 1), bhl1, a);
            st4(nr + 64 + 16 * rb + 4 * g, a);
        }
#pragma unroll
        for (int rb = 0; rb < 4; ++rb) {   // q = pos @ P1 ; qp = q + p1
            f32x4 qv, qpv;
#pragma unroll
            for (int c = 0; c < 4; ++c) {
                int ch = 16 * rb + 4 * g + c;
                float q = p0 * cb[192 + ch] + p1v * cb[256 + ch] + p2v * cb[320 + ch];
                qv[c] = q; qpv[c] = q + cb[128 + ch];
            }
            st4(gr + 16 * rb + 4 * g, qv);
            st4(nr + 16 * rb + 4 * g, qpv);
        }
    }
#undef AF2
}

// pure scan (wstart computed in k_edge; vectorized int4 loads/stores)
__global__ void __launch_bounds__(1024) k_scan(const int* __restrict__ deg,
                                               int* __restrict__ poff) {
    __shared__ int part[1024];
    int t = threadIdx.x;
    int base = t * 64;
    int s = 0;
#pragma unroll
    for (int r = 0; r < 64; r += 4) {
        i32x4 d = *(const i32x4*)(deg + base + r);
        s += ((d[0] + 15) & ~15) + ((d[1] + 15) & ~15)
           + ((d[2] + 15) & ~15) + ((d[3] + 15) & ~15);
    }
    part[t] = s;
    __syncthreads();
    int v = s;
    for (int off = 1; off < 1024; off <<= 1) {
        int add = (t >= off) ? part[t - off] : 0;
        __syncthreads();
        v += add; part[t] = v;
        __syncthreads();
    }
    int run = v - s;   // exclusive prefix
#pragma unroll
    for (int r = 0; r < 64; r += 4) {
        i32x4 d = *(const i32x4*)(deg + base + r);
        i32x4 po;
#pragma unroll
        for (int k = 0; k < 4; ++k) { po[k] = run; run += (d[k] + 15) & ~15; }
        *(i32x4*)(poff + base + r) = po;
    }
    if (t == 1023) poff[NN] = run;
}

// ---- atomic-free scatter using recorded slots ----
__global__ void k_scatter(const int* __restrict__ ei, const int* __restrict__ eslot,
                          const int* __restrict__ poff, int* __restrict__ srtj) {
    int e = blockIdx.x * 256 + threadIdx.x;
    int i = ei[NE + e];
    srtj[poff[i] + eslot[e]] = ei[e] * 192;   // pre-scaled element offset into gsv
}

// ---- persistent fused edge MLP; self-partition, LDS transpose, prefetch rotation ----
__global__ void __launch_bounds__(256) k_edge(
    const unsigned short* __restrict__ gsv, const unsigned short* __restrict__ nad,
    const int* __restrict__ poff, const int* __restrict__ deg,
    const int* __restrict__ srtj, const short* __restrict__ Apack,
    const float* __restrict__ p2b, const float* __restrict__ a2b,
    unsigned short* __restrict__ obf) {
    __shared__ short AwLds[12288];     // 3 layers x 4 rb x 2 s x 64 lanes x 8 bf16
    __shared__ float biasLds[128];     // [0]p2b [64]a2b(x log2e)
    __shared__ unsigned stg[4][768];   // per-wave transpose stage: 64 lanes x 12 words
    {
        const int* gA = (const int*)Apack;
        int* sA = (int*)AwLds;
        for (int i = threadIdx.x; i < 6144; i += 256) sA[i] = gA[i];
        if (threadIdx.x < 64) {
            biasLds[threadIdx.x] = p2b[threadIdx.x];
            biasLds[64 + threadIdx.x] = a2b[threadIdx.x] * 1.44269504088896f;
        }
    }

    int l = threadIdx.x & 63;
    int g = l >> 4, e = l & 15;
    int w = blockIdx.x * 4 + (threadIdx.x >> 6);   // 0..EW-1

    // self-computed tile-balanced partition (overlaps with LDS staging above)
    int tot = poff[NN];
    int node, nodeEnd;
    {
        long long t1l = (long long)w * tot;
        int tgt = (int)(t1l / EW);
        int lo = 0, hi2 = NN;
        while (lo < hi2) { int mid = (lo + hi2) >> 1; if (poff[mid] < tgt) lo = mid + 1; else hi2 = mid; }
        node = lo;
        if (w + 1 == EW) nodeEnd = NN;
        else {
            int tgt2 = (int)((t1l + tot) / EW);
            lo = 0; hi2 = NN;
            while (lo < hi2) { int mid = (lo + hi2) >> 1; if (poff[mid] < tgt2) lo = mid + 1; else hi2 = mid; }
            nodeEnd = lo;
        }
    }
    __syncthreads();

    // destination-centric transpose stage addressing (stride 12 words = 48B)
    unsigned* sbw = stg[threadIdx.x >> 6];
    int wbase = (l & 16) ? 2 : 0;
    int tdst1 = 16 * ((l >= 32) ? 1 : 0) + e;
    unsigned* wp0 = sbw + tdst1 * 12 + wbase;
    unsigned* wp1 = wp0 + 4;
    unsigned* wp2 = sbw + (tdst1 + 32) * 12 + wbase;
    unsigned* wp3 = wp2 + 4;
    const unsigned* rp0 = sbw + l * 12;
    const unsigned* rp1 = rp0 + 4;

#define AW(L, rb, s) (*(const short8*)(AwLds + ((((L) * 4 + (rb)) * 2 + (s)) * 64 + l) * 8))
#define XPOSE(cA, cB, f0, f1)                                              \
    {                                                                      \
        u32x2 _a; _a[0] = cA[0]; _a[1] = cA[1]; *(u32x2*)wp0 = _a;         \
        _a[0] = cB[0]; _a[1] = cB[1]; *(u32x2*)wp1 = _a;                   \
        _a[0] = cA[2]; _a[1] = cA[3]; *(u32x2*)wp2 = _a;                   \
        _a[0] = cB[2]; _a[1] = cB[3]; *(u32x2*)wp3 = _a;                   \
        f0 = __builtin_bit_cast(short8, *(const u32x4*)rp0);               \
        f1 = __builtin_bit_cast(short8, *(const u32x4*)rp1);               \
    }

    while (node < nodeEnd && poff[node + 1] == poff[node]) {
        if (e == 0) {
            unsigned short* op = obf + (size_t)node * 64;
#pragma unroll
            for (int rb = 0; rb < 4; ++rb) *(u32x2*)(op + 16 * rb + 4 * g) = (u32x2)0u;
        }
        ++node;
    }
    if (node >= nodeEnd) return;

    int t0 = poff[node], t1 = poff[node + 1];
    int vend = t0 + deg[node];
    int tendW = poff[nodeEnd];

    // current node constants (adv pre-unpacked to f32)
    const unsigned short* nr = nad + (size_t)node * 128;
    bf16x8 qpA = *(const bf16x8*)(nr + 8 * g);
    bf16x8 qpB = *(const bf16x8*)(nr + 32 + 8 * g);
    f32x4 advf[4];
#pragma unroll
    for (int rb = 0; rb < 4; ++rb) {
        bf16x4 a = *(const bf16x4*)(nr + 64 + 16 * rb + 4 * g);
#pragma unroll
        for (int c = 0; c < 4; ++c) advf[rb][c] = bf2f(a[c]);
    }

    // next-node prefetch state (kept packed)
    int prefN = (node + 1 < NN) ? node + 1 : NN - 1;
    const unsigned short* pr = nad + (size_t)prefN * 128;
    bf16x8 pqpA = *(const bf16x8*)(pr + 8 * g);
    bf16x8 pqpB = *(const bf16x8*)(pr + 32 + 8 * g);
    bf16x4 padv[4];
#pragma unroll
    for (int rb = 0; rb < 4; ++rb)
        padv[rb] = *(const bf16x4*)(pr + 64 + 16 * rb + 4 * g);
    int pt1 = poff[prefN + 1];
    int pdeg = deg[prefN];

    f32x4 num[4], den[4];
#pragma unroll
    for (int rb = 0; rb < 4; ++rb) { num[rb] = (f32x4)0.f; den[rb] = (f32x4)0.f; }

    // edge pipeline prologue
    int j1 = srtj[t0 + 16 + e];
    const unsigned short* g0 = gsv + srtj[t0 + e];
    bf16x8 q0A = *(const bf16x8*)(g0 + 8 * g);
    bf16x8 q0B = *(const bf16x8*)(g0 + 32 + 8 * g);
    bf16x8 svld[4];   // [0..3]=s, [4..7]=v per rb
#pragma unroll
    for (int rb = 0; rb < 4; ++rb)
        svld[rb] = *(const bf16x8*)(g0 + 64 + 32 * rb + 8 * g);

    for (int tb = t0; tb < tendW; tb += 16) {
        int j2 = srtj[tb + 32 + e];                      // 2-ahead (sequential)
        const unsigned short* g1 = gsv + j1;             // 1-ahead gather
        bf16x8 nqA = *(const bf16x8*)(g1 + 8 * g);
        bf16x8 nqB = *(const bf16x8*)(g1 + 32 + 8 * g);

        // u = lrelu(qp_i - q_j) -> bf16 B-frags
        u32x4 buA, buB;
#pragma unroll
        for (int p = 0; p < 4; ++p) {
            float u0 = lrelu(bf2f(qpA[2 * p]) - bf2f(q0A[2 * p]));
            float u1 = lrelu(bf2f(qpA[2 * p + 1]) - bf2f(q0A[2 * p + 1]));
            buA[p] = pk2(u0, u1);
            u0 = lrelu(bf2f(qpB[2 * p]) - bf2f(q0B[2 * p]));
            u1 = lrelu(bf2f(qpB[2 * p + 1]) - bf2f(q0B[2 * p + 1]));
            buB[p] = pk2(u0, u1);
        }
        short8 bu0 = __builtin_bit_cast(short8, buA);
        short8 bu1 = __builtin_bit_cast(short8, buB);

        // layer 1: d^T = P2^T u^T + p2b
        f32x4 acc[4];
#pragma unroll
        for (int rb = 0; rb < 4; ++rb) acc[rb] = *(const f32x4*)(biasLds + 16 * rb + 4 * g);
#pragma unroll
        for (int rb = 0; rb < 4; ++rb) {
            acc[rb] = MFMA(AW(0, rb, 0), bu0, acc[rb]);
            acc[rb] = MFMA(AW(0, rb, 1), bu1, acc[rb]);
        }
        f32x4 d4[4];
#pragma unroll
        for (int rb = 0; rb < 4; ++rb)
#pragma unroll
            for (int c = 0; c < 4; ++c) d4[rb][c] = lrelu(acc[rb][c]);
        u32x4 dA, dB;
        dA[0] = pk2(d4[0][0], d4[0][1]); dA[1] = pk2(d4[0][2], d4[0][3]);
        dA[2] = pk2(d4[1][0], d4[1][1]); dA[3] = pk2(d4[1][2], d4[1][3]);
        dB[0] = pk2(d4[2][0], d4[2][1]); dB[1] = pk2(d4[2][2], d4[2][3]);
        dB[2] = pk2(d4[3][0], d4[3][1]); dB[3] = pk2(d4[3][2], d4[3][3]);
        short8 bd0, bd1;
        XPOSE(dA, dB, bd0, bd1);

        // layer 2 init: adv_i - as1_j (s = svld[rb][0..3])
#pragma unroll
        for (int rb = 0; rb < 4; ++rb) {
            f32x4 t;
#pragma unroll
            for (int c = 0; c < 4; ++c) t[c] = advf[rb][c] - bf2f(svld[rb][c]);
            acc[rb] = t;
        }
#pragma unroll
        for (int rb = 0; rb < 4; ++rb) {
            acc[rb] = MFMA(AW(1, rb, 0), bd0, acc[rb]);
            acc[rb] = MFMA(AW(1, rb, 1), bd1, acc[rb]);
        }
        u32x4 tA, tB;
        tA[0] = pk2(frelu(acc[0][0]), frelu(acc[0][1]));
        tA[1] = pk2(frelu(acc[0][2]), frelu(acc[0][3]));
        tA[2] = pk2(frelu(acc[1][0]), frelu(acc[1][1]));
        tA[3] = pk2(frelu(acc[1][2]), frelu(acc[1][3]));
        tB[0] = pk2(frelu(acc[2][0]), frelu(acc[2][1]));
        tB[1] = pk2(frelu(acc[2][2]), frelu(acc[2][3]));
        tB[2] = pk2(frelu(acc[3][0]), frelu(acc[3][1]));
        tB[3] = pk2(frelu(acc[3][2]), frelu(acc[3][3]));
        short8 bt0, bt1;
        XPOSE(tA, tB, bt0, bt1);

        // layer 3: alpha2^T = (A2 log2e)^T t^T + a2 log2e
#pragma unroll
        for (int rb = 0; rb < 4; ++rb) acc[rb] = *(const f32x4*)(biasLds + 64 + 16 * rb + 4 * g);
#pragma unroll
        for (int rb = 0; rb < 4; ++rb) {
            acc[rb] = MFMA(AW(2, rb, 0), bt0, acc[rb]);
            acc[rb] = MFMA(AW(2, rb, 1), bt1, acc[rb]);
        }

        // softmax accumulate: exp(relu(alpha)) = exp2(relu(alpha*log2e))
        bool ok = (tb + e) < vend;
#pragma unroll
        for (int rb = 0; rb < 4; ++rb) {
#pragma unroll
            for (int c = 0; c < 4; ++c) {
                float a = frelu(acc[rb][c]);
                float ew = ok ? exp2f(a) : 0.f;
                den[rb][c] += ew;
                num[rb][c] += ew * (bf2f(svld[rb][4 + c]) + d4[rb][c]);
            }
        }
        // svld dead -> next tile's combined {s,v} gather (4 b128)
#pragma unroll
        for (int rb = 0; rb < 4; ++rb)
            svld[rb] = *(const bf16x8*)(g1 + 64 + 32 * rb + 8 * g);

        q0A = nqA; q0B = nqB; j1 = j2;

        // node epilogue
        if (tb + 16 >= t1) {
#pragma unroll
            for (int m = 1; m < 16; m <<= 1) {
#pragma unroll
                for (int rb = 0; rb < 4; ++rb)
#pragma unroll
                    for (int c = 0; c < 4; ++c) {
                        num[rb][c] += __shfl_xor(num[rb][c], m);
                        den[rb][c] += __shfl_xor(den[rb][c], m);
                    }
            }
            if (e == 0) {
                unsigned short* op = obf + (size_t)node * 64;
#pragma unroll
                for (int rb = 0; rb < 4; ++rb) {
                    f32x4 ov;
#pragma unroll
                    for (int c = 0; c < 4; ++c)
                        ov[c] = num[rb][c] * __builtin_amdgcn_rcpf(den[rb][c] + 1e-16f);
                    u32x2 ow; ow[0] = pk2(ov[0], ov[1]); ow[1] = pk2(ov[2], ov[3]);
                    *(u32x2*)(op + 16 * rb + 4 * g) = ow;
                }
            }
            ++node;
            if (node < nodeEnd && node == prefN && pt1 != t1) {
                t0 = t1; t1 = pt1; vend = t0 + pdeg;
                qpA = pqpA; qpB = pqpB;
#pragma unroll
                for (int rb = 0; rb < 4; ++rb)
#pragma unroll
                    for (int c = 0; c < 4; ++c) advf[rb][c] = bf2f(padv[rb][c]);
            } else {
                while (node < nodeEnd && poff[node + 1] == t1) {
                    if (e == 0) {
                        unsigned short* op = obf + (size_t)node * 64;
#pragma unroll
                        for (int rb = 0; rb < 4; ++rb)
                            *(u32x2*)(op + 16 * rb + 4 * g) = (u32x2)0u;
                    }
                    ++node;
                }
                if (node < nodeEnd) {
                    t0 = t1; t1 = poff[node + 1];
                    vend = t0 + deg[node];
                    const unsigned short* nr2 = nad + (size_t)node * 128;
                    qpA = *(const bf16x8*)(nr2 + 8 * g);
                    qpB = *(const bf16x8*)(nr2 + 32 + 8 * g);
#pragma unroll
                    for (int rb = 0; rb < 4; ++rb) {
                        bf16x4 a = *(const bf16x4*)(nr2 + 64 + 16 * rb + 4 * g);
#pragma unroll
                        for (int c = 0; c < 4; ++c) advf[rb][c] = bf2f(a[c]);
                    }
                }
            }
            if (node < nodeEnd) {
                prefN = (node + 1 < NN) ? node + 1 : NN - 1;
                const unsigned short* pr2 = nad + (size_t)prefN * 128;
                pqpA = *(const bf16x8*)(pr2 + 8 * g);
                pqpB = *(const bf16x8*)(pr2 + 32 + 8 * g);
#pragma unroll
                for (int rb = 0; rb < 4; ++rb)
                    padv[rb] = *(const bf16x4*)(pr2 + 64 + 16 * rb + 4 * g);
                pt1 = poff[prefN + 1];
                pdeg = deg[prefN];
#pragma unroll
                for (int rb = 0; rb < 4; ++rb) { num[rb] = (f32x4)0.f; den[rb] = (f32x4)0.f; }
            }
        }
    }
#undef AW
#undef XPOSE
}

// ---- out = relu(o @ Wout + bout); o read directly as bf16 B-frags ----
__global__ void __launch_bounds__(512) k_out(const unsigned short* __restrict__ obf,
                                             const short* __restrict__ Apack,
                                             const float* __restrict__ bout,
                                             float* __restrict__ out) {
    __shared__ short Ah[4096], Al[4096];
    __shared__ float bb[64];
    {
        const int* gh = (const int*)(Apack + 3 * 4096);
        const int* gl = (const int*)(Apack + 4 * 4096);
        int* sh = (int*)Ah; int* sl = (int*)Al;
        for (int i = threadIdx.x; i < 2048; i += 512) { sh[i] = gh[i]; sl[i] = gl[i]; }
        if (threadIdx.x < 64) bb[threadIdx.x] = bout[threadIdx.x];
    }
    __syncthreads();
    int l = threadIdx.x & 63, g = l >> 4;
    int tile = blockIdx.x * 8 + (threadIdx.x >> 6);   // 0..4095
    int nbase = tile * 16;
    const unsigned short* op = obf + (size_t)(nbase + (l & 15)) * 64;
    short8 b0 = __builtin_bit_cast(short8, *(const bf16x8*)(op + 8 * g));
    short8 b1 = __builtin_bit_cast(short8, *(const bf16x8*)(op + 32 + 8 * g));
#define AF(arr, rb, s) (*(const short8*)(arr + (((rb) * 2 + (s)) * 64 + l) * 8))
    f32x4 acc[4];
#pragma unroll
    for (int rb = 0; rb < 4; ++rb) acc[rb] = *(const f32x4*)(bb + 16 * rb + 4 * g);
#pragma unroll
    for (int rb = 0; rb < 4; ++rb) {
        acc[rb] = MFMA(AF(Ah, rb, 0), b0, acc[rb]);
        acc[rb] = MFMA(AF(Ah, rb, 1), b1, acc[rb]);
        acc[rb] = MFMA(AF(Al, rb, 0), b0, acc[rb]);
        acc[rb] = MFMA(AF(Al, rb, 1), b1, acc[rb]);
    }
#undef AF
    float* outp = out + (size_t)(nbase + (l & 15)) * 64;
#pragma unroll
    for (int rb = 0; rb < 4; ++rb) {
        f32x4 r;
#pragma unroll
        for (int c = 0; c < 4; ++c) r[c] = frelu(acc[rb][c]);
        *(f32x4*)(outp + 16 * rb + 4 * g) = r;
    }
}

extern "C" void kernel_launch(void* const* d_in, const int* in_sizes, int n_in,
                              void* d_out, int out_size, void* d_ws, size_t ws_size,
                              hipStream_t stream) {
    const float* x    = (const float*)d_in[0];
    const float* pos  = (const float*)d_in[1];
    const int*   ei   = (const int*)d_in[2];
    const float* Win  = (const float*)d_in[3];
    const float* bin  = (const float*)d_in[4];
    const float* Wout = (const float*)d_in[5];
    const float* bout = (const float*)d_in[6];
    const float* Wlin = (const float*)d_in[7];
    const float* Wsrc = (const float*)d_in[8];
    const float* Wdst = (const float*)d_in[9];
    const float* P1   = (const float*)d_in[10];
    const float* p1   = (const float*)d_in[11];
    const float* P2   = (const float*)d_in[12];
    const float* p2   = (const float*)d_in[13];
    const float* A1   = (const float*)d_in[14];
    const float* a1   = (const float*)d_in[15];
    const float* A2   = (const float*)d_in[16];
    const float* a2   = (const float*)d_in[17];
    float* out = (float*)d_out;

    char* w = (char*)d_ws;
    short* Apck = (short*)w; w += 9 * 4096 * 2;
    unsigned short* obf = (unsigned short*)w; w += (size_t)NN * 64 * 2;
    unsigned short* gsv = (unsigned short*)w; w += (size_t)NN * 192 * 2;
    unsigned short* nad = (unsigned short*)w; w += (size_t)NN * 128 * 2;
    int* deg    = (int*)w; w += (size_t)NN * 4;
    int* poffp  = (int*)w; w += (size_t)(NN + 16) * 4;
    int* eslot  = (int*)w; w += (size_t)NE * 4;
    int* srtj   = (int*)w; w += (size_t)2 * NE * 4;

    k_pack<<<18 + 64, 256, 0, stream>>>(P2, A1, A2, Wout, Win, Wlin, Wdst, Wsrc,
                                        Apck, deg);
    k_front<<<1024 + 4096 + 2048, 256, 0, stream>>>(x, pos, Apck, bin, a1, P1, p1,
                                                    ei, deg, eslot, srtj, gsv, nad);
    k_scan<<<1, 1024, 0, stream>>>(deg, poffp);
    k_scatter<<<NE / 256, 256, 0, stream>>>(ei, eslot, poffp, srtj);
    k_edge<<<EW / 4, 256, 0, stream>>>(gsv, nad, poffp, deg, srtj, Apck,
                                       p2, a2, obf);
    k_out<<<512, 512, 0, stream>>>(obf, Apck, bout, out);
}

// Round 16
// 306.215 us; speedup vs baseline: 1.0407x; 1.0407x over previous
//
#include <hip/hip_runtime.h>
#include <hip/hip_bf16.h>

#define NN 65536
#define NE 1048576
#define EW 4096   // persistent waves in k_edge (1024 blocks x 4 waves = 4 blk/CU)

typedef __attribute__((ext_vector_type(8))) short short8;
typedef __attribute__((ext_vector_type(8))) unsigned short bf16x8;
typedef __attribute__((ext_vector_type(4))) unsigned short bf16x4;
typedef __attribute__((ext_vector_type(4))) float f32x4;
typedef __attribute__((ext_vector_type(4))) unsigned int u32x4;
typedef __attribute__((ext_vector_type(2))) unsigned int u32x2;
typedef __attribute__((ext_vector_type(4))) int i32x4;

__device__ __forceinline__ float lrelu(float x) { return fmaxf(x, 0.01f * x); }
__device__ __forceinline__ float frelu(float x) { return fmaxf(x, 0.f); }
__device__ __forceinline__ short f2bf(float f) {
    __hip_bfloat16 h = __float2bfloat16(f);
    return *reinterpret_cast<short*>(&h);
}
__device__ __forceinline__ float bf2f(unsigned short s) {
    return __uint_as_float(((unsigned)s) << 16);
}
// single-instruction packed f32x2 -> bf16x2 (RNE), lo in low half
__device__ __forceinline__ unsigned pk2(float lo, float hi) {
    unsigned r;
    asm("v_cvt_pk_bf16_f32 %0, %1, %2" : "=v"(r) : "v"(lo), "v"(hi));
    return r;
}
__device__ __forceinline__ void st4(unsigned short* p, f32x4 v) {
    u32x2 w; w[0] = pk2(v[0], v[1]); w[1] = pk2(v[2], v[3]);
    *(u32x2*)p = w;
}
// DPP quad-perm add: x + lane_xor_m(x) for m=1 (ctrl 0xB1) / m=2 (ctrl 0x4E); VALU-only
template <int CTRL>
__device__ __forceinline__ float dppadd(float x) {
    int sh = __builtin_amdgcn_update_dpp(0, __float_as_int(x), CTRL, 0xF, 0xF, true);
    return x + __int_as_float(sh);
}

// ---- pack MFMA A-frags: 0=P2 1=A1 2=A2(x log2e) 3=Wout_hi 4=Wout_lo 5=Win 6=Wlin
//      7=Wda(=Wdst@A1) 8=Wsa(=Wsrc@A1); blocks >=18 zero deg ----
__global__ void k_pack(const float* __restrict__ P2, const float* __restrict__ A1,
                       const float* __restrict__ A2, const float* __restrict__ Wout,
                       const float* __restrict__ Win, const float* __restrict__ Wlin,
                       const float* __restrict__ Wdst, const float* __restrict__ Wsrc,
                       short* __restrict__ Apack, int* __restrict__ deg) {
    if (blockIdx.x >= 18) {            // deg zeroing: 64 blocks x 256 x 4 ints
        int i = (blockIdx.x - 18) * 1024 + threadIdx.x * 4;
        *(i32x4*)(deg + i) = (i32x4)0;
        return;
    }
    int idx = blockIdx.x * 256 + threadIdx.x;   // fid*512 + (rb*2+s)*64 + l
    if (idx >= 9 * 512) return;
    int l = idx & 63, s = (idx >> 6) & 1, rb = (idx >> 7) & 3, fid = idx >> 9;
    const float* Wt[7] = {P2, A1, A2, Wout, Wout, Win, Wlin};
    bool lo = (fid == 4);
#pragma unroll
    for (int b = 0; b < 8; ++b) {
        int in = 32 * s + 8 * (l >> 4) + b;
        int out = 16 * rb + (l & 15);
        float w;
        if (fid >= 7) {
            const float* Wsel = (fid == 7) ? Wdst : Wsrc;
            float acc = 0.f;
            for (int k = 0; k < 64; ++k) acc += Wsel[in * 64 + k] * A1[k * 64 + out];
            w = acc;
        } else {
            w = Wt[fid][in * 64 + out];
            if (fid == 2) w *= 1.44269504088896f;   // fold exp->exp2
        }
        short hi = f2bf(w);
        Apack[idx * 8 + b] = lo ? f2bf(w - bf2f((unsigned short)hi)) : hi;
    }
}

// packed-bf16 transpose via bpermute (used by k_front node blocks only)
__device__ __forceinline__ short8 mkfrag(u32x4 c, int la4, int lb4, bool hi) {
    u32x4 r;
    unsigned a0 = (unsigned)__builtin_amdgcn_ds_bpermute(la4, (int)c[0]);
    unsigned a1 = (unsigned)__builtin_amdgcn_ds_bpermute(la4, (int)c[1]);
    unsigned b0 = (unsigned)__builtin_amdgcn_ds_bpermute(la4, (int)c[2]);
    unsigned b1 = (unsigned)__builtin_amdgcn_ds_bpermute(la4, (int)c[3]);
    r[0] = hi ? b0 : a0; r[1] = hi ? b1 : a1;
    a0 = (unsigned)__builtin_amdgcn_ds_bpermute(lb4, (int)c[0]);
    a1 = (unsigned)__builtin_amdgcn_ds_bpermute(lb4, (int)c[1]);
    b0 = (unsigned)__builtin_amdgcn_ds_bpermute(lb4, (int)c[2]);
    b1 = (unsigned)__builtin_amdgcn_ds_bpermute(lb4, (int)c[3]);
    r[2] = hi ? b0 : a0; r[3] = hi ? b1 : a1;
    return __builtin_bit_cast(short8, r);
}

#define MFMA(a, b, c) __builtin_amdgcn_mfma_f32_16x16x32_bf16(a, b, c, 0, 0, 0)

// ---- fused front: node MFMA (1024) || hist+slot-record (4096) || srtj zero (2048)
// gsv row (192 bf16): [0..63]=q ; [64+32rb+8g+0..3]=s ; [64+32rb+8g+4..7]=v
__global__ void __launch_bounds__(256) k_front(
    const float* __restrict__ x, const float* __restrict__ pos,
    const short* __restrict__ Apack,
    const float* __restrict__ bin, const float* __restrict__ a1,
    const float* __restrict__ P1, const float* __restrict__ p1,
    const int* __restrict__ ei, int* __restrict__ deg, int* __restrict__ eslot,
    int* __restrict__ srtj,
    unsigned short* __restrict__ gsv, unsigned short* __restrict__ nad) {
    if (blockIdx.x >= 5120) {          // srtj zeroing: 2048 blocks x 256 x 4 ints
        int i = (blockIdx.x - 5120) * 1024 + threadIdx.x * 4;
        *(i32x4*)(srtj + i) = (i32x4)0;
        return;
    }
    if (blockIdx.x >= 1024) {          // histogram + slot record
        int e = (blockIdx.x - 1024) * 256 + threadIdx.x;
        eslot[e] = atomicAdd(&deg[ei[NE + e]], 1);
        return;
    }
    __shared__ short AW2[4 * 4096];   // fids 5..8: Win, Wlin, Wda, Wsa
    __shared__ float cb[384];         // [0]bin [64]a1 [128]p1 [192..384]P1
    {
        const int* gA = (const int*)(Apack + 5 * 4096);
        int* sA = (int*)AW2;
        for (int i = threadIdx.x; i < 8192; i += 256) sA[i] = gA[i];
        if (threadIdx.x < 64) {
            cb[threadIdx.x] = bin[threadIdx.x];
            cb[64 + threadIdx.x] = a1[threadIdx.x];
            cb[128 + threadIdx.x] = p1[threadIdx.x];
        }
        if (threadIdx.x < 192) cb[192 + threadIdx.x] = P1[threadIdx.x];
    }
    __syncthreads();
    int l = threadIdx.x & 63, g = l >> 4, e = l & 15;
    int la4 = (32 * (g & 1) + e) * 4, lb4 = la4 + 64;
    bool hi = (g >= 2);
#define AF2(f, rb, s) (*(const short8*)(AW2 + ((((f) * 4 + (rb)) * 2 + (s)) * 64 + l) * 8))
    {
        int tile = blockIdx.x * 4 + (threadIdx.x >> 6);   // 0..4095, 1 tile/wave
        int n = tile * 16 + e;
        float p0 = pos[n * 3 + 0], p1v = pos[n * 3 + 1], p2v = pos[n * 3 + 2];
        const float* xr = x + (size_t)n * 64 + 8 * g;
        f32x4 x00 = *(const f32x4*)(xr), x01 = *(const f32x4*)(xr + 4);
        f32x4 x10 = *(const f32x4*)(xr + 32), x11 = *(const f32x4*)(xr + 36);
        short8 xh[2], xl[2];
#pragma unroll
        for (int b = 0; b < 4; ++b) {
            float f;
            f = x00[b]; xh[0][b] = f2bf(f);     xl[0][b] = f2bf(f - bf2f((unsigned short)xh[0][b]));
            f = x01[b]; xh[0][b + 4] = f2bf(f); xl[0][b + 4] = f2bf(f - bf2f((unsigned short)xh[0][b + 4]));
            f = x10[b]; xh[1][b] = f2bf(f);     xl[1][b] = f2bf(f - bf2f((unsigned short)xh[1][b]));
            f = x11[b]; xh[1][b + 4] = f2bf(f); xl[1][b + 4] = f2bf(f - bf2f((unsigned short)xh[1][b + 4]));
        }
        // h = relu(Win^T x + bin)
        f32x4 acc[4];
#pragma unroll
        for (int rb = 0; rb < 4; ++rb) acc[rb] = *(const f32x4*)(cb + 16 * rb + 4 * g);
#pragma unroll
        for (int rb = 0; rb < 4; ++rb) {
            acc[rb] = MFMA(AF2(0, rb, 0), xh[0], acc[rb]);
            acc[rb] = MFMA(AF2(0, rb, 1), xh[1], acc[rb]);
            acc[rb] = MFMA(AF2(0, rb, 0), xl[0], acc[rb]);
            acc[rb] = MFMA(AF2(0, rb, 1), xl[1], acc[rb]);
        }
        f32x4 hv[4], res[4];
#pragma unroll
        for (int rb = 0; rb < 4; ++rb)
#pragma unroll
            for (int c = 0; c < 4; ++c) {
                float f = frelu(acc[rb][c]);
                hv[rb][c] = f;
                res[rb][c] = f - bf2f((unsigned short)f2bf(f));
            }
        u32x4 HhA, HhB, HlA, HlB;
        HhA[0] = pk2(hv[0][0], hv[0][1]); HhA[1] = pk2(hv[0][2], hv[0][3]);
        HhA[2] = pk2(hv[1][0], hv[1][1]); HhA[3] = pk2(hv[1][2], hv[1][3]);
        HhB[0] = pk2(hv[2][0], hv[2][1]); HhB[1] = pk2(hv[2][2], hv[2][3]);
        HhB[2] = pk2(hv[3][0], hv[3][1]); HhB[3] = pk2(hv[3][2], hv[3][3]);
        HlA[0] = pk2(res[0][0], res[0][1]); HlA[1] = pk2(res[0][2], res[0][3]);
        HlA[2] = pk2(res[1][0], res[1][1]); HlA[3] = pk2(res[1][2], res[1][3]);
        HlB[0] = pk2(res[2][0], res[2][1]); HlB[1] = pk2(res[2][2], res[2][3]);
        HlB[2] = pk2(res[3][0], res[3][1]); HlB[3] = pk2(res[3][2], res[3][3]);
        short8 bhh0 = mkfrag(HhA, la4, lb4, hi), bhh1 = mkfrag(HhB, la4, lb4, hi);
        short8 bhl0 = mkfrag(HlA, la4, lb4, hi), bhl1 = mkfrag(HlB, la4, lb4, hi);

        unsigned short* gr = gsv + (size_t)n * 192;
        unsigned short* nr = nad + (size_t)n * 128;
        f32x4 vres[4];
#pragma unroll
        for (int rb = 0; rb < 4; ++rb) {   // v = h @ Wlin (regs)
            f32x4 a = (f32x4)0.f;
            a = MFMA(AF2(1, rb, 0), bhh0, a);
            a = MFMA(AF2(1, rb, 1), bhh1, a);
            a = MFMA(AF2(1, rb, 0), bhl0, a);
            a = MFMA(AF2(1, rb, 1), bhl1, a);
            vres[rb] = a;
        }
#pragma unroll
        for (int rb = 0; rb < 4; ++rb) {   // s = h @ Wsa; write combined {s,v} b128
            f32x4 a = (f32x4)0.f;
            a = MFMA(AF2(3, rb, 0), bhh0, a);
            a = MFMA(AF2(3, rb, 1), bhh1, a);
            a = MFMA(AF2(3, rb, 0), bhl0, a);
            a = MFMA(AF2(3, rb, 1), bhl1, a);
            u32x4 wv4;
            wv4[0] = pk2(a[0], a[1]); wv4[1] = pk2(a[2], a[3]);
            wv4[2] = pk2(vres[rb][0], vres[rb][1]); wv4[3] = pk2(vres[rb][2], vres[rb][3]);
            *(u32x4*)(gr + 64 + 32 * rb + 8 * g) = wv4;
        }
#pragma unroll
        for (int rb = 0; rb < 4; ++rb) {   // ad = h @ Wda + a1
            f32x4 a = *(const f32x4*)(cb + 64 + 16 * rb + 4 * g);
            a = MFMA(AF2(2, rb, 0), bhh0, a);
            a = MFMA(AF2(2, rb, 1), bhh1, a);
            a = MFMA(AF2(2, rb, 0), bhl0, a);
            a = MFMA(AF2(2, rb, 1), bhl1, a);
            st4(nr + 64 + 16 * rb + 4 * g, a);
        }
#pragma unroll
        for (int rb = 0; rb < 4; ++rb) {   // q = pos @ P1 ; qp = q + p1
            f32x4 qv, qpv;
#pragma unroll
            for (int c = 0; c < 4; ++c) {
                int ch = 16 * rb + 4 * g + c;
                float q = p0 * cb[192 + ch] + p1v * cb[256 + ch] + p2v * cb[320 + ch];
                qv[c] = q; qpv[c] = q + cb[128 + ch];
            }
            st4(gr + 16 * rb + 4 * g, qv);
            st4(nr + 16 * rb + 4 * g, qpv);
        }
    }
#undef AF2
}

// pure scan (wstart computed in k_edge; vectorized int4 loads/stores)
__global__ void __launch_bounds__(1024) k_scan(const int* __restrict__ deg,
                                               int* __restrict__ poff) {
    __shared__ int part[1024];
    int t = threadIdx.x;
    int base = t * 64;
    int s = 0;
#pragma unroll
    for (int r = 0; r < 64; r += 4) {
        i32x4 d = *(const i32x4*)(deg + base + r);
        s += ((d[0] + 15) & ~15) + ((d[1] + 15) & ~15)
           + ((d[2] + 15) & ~15) + ((d[3] + 15) & ~15);
    }
    part[t] = s;
    __syncthreads();
    int v = s;
    for (int off = 1; off < 1024; off <<= 1) {
        int add = (t >= off) ? part[t - off] : 0;
        __syncthreads();
        v += add; part[t] = v;
        __syncthreads();
    }
    int run = v - s;   // exclusive prefix
#pragma unroll
    for (int r = 0; r < 64; r += 4) {
        i32x4 d = *(const i32x4*)(deg + base + r);
        i32x4 po;
#pragma unroll
        for (int k = 0; k < 4; ++k) { po[k] = run; run += (d[k] + 15) & ~15; }
        *(i32x4*)(poff + base + r) = po;
    }
    if (t == 1023) poff[NN] = run;
}

// ---- atomic-free scatter using recorded slots ----
__global__ void k_scatter(const int* __restrict__ ei, const int* __restrict__ eslot,
                          const int* __restrict__ poff, int* __restrict__ srtj) {
    int e = blockIdx.x * 256 + threadIdx.x;
    int i = ei[NE + e];
    srtj[poff[i] + eslot[e]] = ei[e] * 192;   // pre-scaled element offset into gsv
}

// ---- persistent fused edge MLP; self-partition, LDS transpose, prefetch rotation ----
__global__ void __launch_bounds__(256) k_edge(
    const unsigned short* __restrict__ gsv, const unsigned short* __restrict__ nad,
    const int* __restrict__ poff, const int* __restrict__ deg,
    const int* __restrict__ srtj, const short* __restrict__ Apack,
    const float* __restrict__ p2b, const float* __restrict__ a2b,
    unsigned short* __restrict__ obf) {
    __shared__ short AwLds[12288];     // 3 layers x 4 rb x 2 s x 64 lanes x 8 bf16
    __shared__ float biasLds[128];     // [0]p2b [64]a2b(x log2e)
    __shared__ unsigned stg[4][768];   // per-wave transpose stage: 64 lanes x 12 words
    {
        const int* gA = (const int*)Apack;
        int* sA = (int*)AwLds;
        for (int i = threadIdx.x; i < 6144; i += 256) sA[i] = gA[i];
        if (threadIdx.x < 64) {
            biasLds[threadIdx.x] = p2b[threadIdx.x];
            biasLds[64 + threadIdx.x] = a2b[threadIdx.x] * 1.44269504088896f;
        }
    }

    int l = threadIdx.x & 63;
    int g = l >> 4, e = l & 15;
    int w = blockIdx.x * 4 + (threadIdx.x >> 6);   // 0..EW-1

    // self-computed tile-balanced partition (overlaps with LDS staging above)
    int tot = poff[NN];
    int node, nodeEnd;
    {
        long long t1l = (long long)w * tot;
        int tgt = (int)(t1l / EW);
        int lo = 0, hi2 = NN;
        while (lo < hi2) { int mid = (lo + hi2) >> 1; if (poff[mid] < tgt) lo = mid + 1; else hi2 = mid; }
        node = lo;
        if (w + 1 == EW) nodeEnd = NN;
        else {
            int tgt2 = (int)((t1l + tot) / EW);
            lo = 0; hi2 = NN;
            while (lo < hi2) { int mid = (lo + hi2) >> 1; if (poff[mid] < tgt2) lo = mid + 1; else hi2 = mid; }
            nodeEnd = lo;
        }
    }
    __syncthreads();

    // destination-centric transpose stage addressing (stride 12 words = 48B)
    unsigned* sbw = stg[threadIdx.x >> 6];
    int wbase = (l & 16) ? 2 : 0;
    int tdst1 = 16 * ((l >= 32) ? 1 : 0) + e;
    unsigned* wp0 = sbw + tdst1 * 12 + wbase;
    unsigned* wp1 = wp0 + 4;
    unsigned* wp2 = sbw + (tdst1 + 32) * 12 + wbase;
    unsigned* wp3 = wp2 + 4;
    const unsigned* rp0 = sbw + l * 12;
    const unsigned* rp1 = rp0 + 4;

#define AW(L, rb, s) (*(const short8*)(AwLds + ((((L) * 4 + (rb)) * 2 + (s)) * 64 + l) * 8))
#define XPOSE(cA, cB, f0, f1)                                              \
    {                                                                      \
        u32x2 _a; _a[0] = cA[0]; _a[1] = cA[1]; *(u32x2*)wp0 = _a;         \
        _a[0] = cB[0]; _a[1] = cB[1]; *(u32x2*)wp1 = _a;                   \
        _a[0] = cA[2]; _a[1] = cA[3]; *(u32x2*)wp2 = _a;                   \
        _a[0] = cB[2]; _a[1] = cB[3]; *(u32x2*)wp3 = _a;                   \
        f0 = __builtin_bit_cast(short8, *(const u32x4*)rp0);               \
        f1 = __builtin_bit_cast(short8, *(const u32x4*)rp1);               \
    }

    while (node < nodeEnd && poff[node + 1] == poff[node]) {
        if (e == 0) {
            unsigned short* op = obf + (size_t)node * 64;
#pragma unroll
            for (int rb = 0; rb < 4; ++rb) *(u32x2*)(op + 16 * rb + 4 * g) = (u32x2)0u;
        }
        ++node;
    }
    if (node >= nodeEnd) return;

    int t0 = poff[node], t1 = poff[node + 1];
    int vend = t0 + deg[node];
    int tendW = poff[nodeEnd];

    // current node constants (adv pre-unpacked to f32)
    const unsigned short* nr = nad + (size_t)node * 128;
    bf16x8 qpA = *(const bf16x8*)(nr + 8 * g);
    bf16x8 qpB = *(const bf16x8*)(nr + 32 + 8 * g);
    f32x4 advf[4];
#pragma unroll
    for (int rb = 0; rb < 4; ++rb) {
        bf16x4 a = *(const bf16x4*)(nr + 64 + 16 * rb + 4 * g);
#pragma unroll
        for (int c = 0; c < 4; ++c) advf[rb][c] = bf2f(a[c]);
    }

    // next-node prefetch state (kept packed)
    int prefN = (node + 1 < NN) ? node + 1 : NN - 1;
    const unsigned short* pr = nad + (size_t)prefN * 128;
    bf16x8 pqpA = *(const bf16x8*)(pr + 8 * g);
    bf16x8 pqpB = *(const bf16x8*)(pr + 32 + 8 * g);
    bf16x4 padv[4];
#pragma unroll
    for (int rb = 0; rb < 4; ++rb)
        padv[rb] = *(const bf16x4*)(pr + 64 + 16 * rb + 4 * g);
    int pt1 = poff[prefN + 1];
    int pdeg = deg[prefN];

    f32x4 num[4], den[4];
#pragma unroll
    for (int rb = 0; rb < 4; ++rb) { num[rb] = (f32x4)0.f; den[rb] = (f32x4)0.f; }

    // edge pipeline prologue
    int j1 = srtj[t0 + 16 + e];
    const unsigned short* g0 = gsv + srtj[t0 + e];
    bf16x8 q0A = *(const bf16x8*)(g0 + 8 * g);
    bf16x8 q0B = *(const bf16x8*)(g0 + 32 + 8 * g);
    bf16x8 svld[4];   // [0..3]=s, [4..7]=v per rb
#pragma unroll
    for (int rb = 0; rb < 4; ++rb)
        svld[rb] = *(const bf16x8*)(g0 + 64 + 32 * rb + 8 * g);

    for (int tb = t0; tb < tendW; tb += 16) {
        int j2 = srtj[tb + 32 + e];                      // 2-ahead (sequential)
        const unsigned short* g1 = gsv + j1;             // 1-ahead gather
        bf16x8 nqA = *(const bf16x8*)(g1 + 8 * g);
        bf16x8 nqB = *(const bf16x8*)(g1 + 32 + 8 * g);

        // u = lrelu(qp_i - q_j) -> bf16 B-frags
        u32x4 buA, buB;
#pragma unroll
        for (int p = 0; p < 4; ++p) {
            float u0 = lrelu(bf2f(qpA[2 * p]) - bf2f(q0A[2 * p]));
            float u1 = lrelu(bf2f(qpA[2 * p + 1]) - bf2f(q0A[2 * p + 1]));
            buA[p] = pk2(u0, u1);
            u0 = lrelu(bf2f(qpB[2 * p]) - bf2f(q0B[2 * p]));
            u1 = lrelu(bf2f(qpB[2 * p + 1]) - bf2f(q0B[2 * p + 1]));
            buB[p] = pk2(u0, u1);
        }
        short8 bu0 = __builtin_bit_cast(short8, buA);
        short8 bu1 = __builtin_bit_cast(short8, buB);

        // layer 1: d^T = P2^T u^T + p2b
        f32x4 acc[4];
#pragma unroll
        for (int rb = 0; rb < 4; ++rb) acc[rb] = *(const f32x4*)(biasLds + 16 * rb + 4 * g);
#pragma unroll
        for (int rb = 0; rb < 4; ++rb) {
            acc[rb] = MFMA(AW(0, rb, 0), bu0, acc[rb]);
            acc[rb] = MFMA(AW(0, rb, 1), bu1, acc[rb]);
        }
        f32x4 d4[4];
#pragma unroll
        for (int rb = 0; rb < 4; ++rb)
#pragma unroll
            for (int c = 0; c < 4; ++c) d4[rb][c] = lrelu(acc[rb][c]);
        u32x4 dA, dB;
        dA[0] = pk2(d4[0][0], d4[0][1]); dA[1] = pk2(d4[0][2], d4[0][3]);
        dA[2] = pk2(d4[1][0], d4[1][1]); dA[3] = pk2(d4[1][2], d4[1][3]);
        dB[0] = pk2(d4[2][0], d4[2][1]); dB[1] = pk2(d4[2][2], d4[2][3]);
        dB[2] = pk2(d4[3][0], d4[3][1]); dB[3] = pk2(d4[3][2], d4[3][3]);
        short8 bd0, bd1;
        XPOSE(dA, dB, bd0, bd1);

        // layer 2 init: adv_i - as1_j (s = svld[rb][0..3])
#pragma unroll
        for (int rb = 0; rb < 4; ++rb) {
            f32x4 t;
#pragma unroll
            for (int c = 0; c < 4; ++c) t[c] = advf[rb][c] - bf2f(svld[rb][c]);
            acc[rb] = t;
        }
#pragma unroll
        for (int rb = 0; rb < 4; ++rb) {
            acc[rb] = MFMA(AW(1, rb, 0), bd0, acc[rb]);
            acc[rb] = MFMA(AW(1, rb, 1), bd1, acc[rb]);
        }
        u32x4 tA, tB;
        tA[0] = pk2(frelu(acc[0][0]), frelu(acc[0][1]));
        tA[1] = pk2(frelu(acc[0][2]), frelu(acc[0][3]));
        tA[2] = pk2(frelu(acc[1][0]), frelu(acc[1][1]));
        tA[3] = pk2(frelu(acc[1][2]), frelu(acc[1][3]));
        tB[0] = pk2(frelu(acc[2][0]), frelu(acc[2][1]));
        tB[1] = pk2(frelu(acc[2][2]), frelu(acc[2][3]));
        tB[2] = pk2(frelu(acc[3][0]), frelu(acc[3][1]));
        tB[3] = pk2(frelu(acc[3][2]), frelu(acc[3][3]));
        short8 bt0, bt1;
        XPOSE(tA, tB, bt0, bt1);

        // layer 3: alpha2^T = (A2 log2e)^T t^T + a2 log2e
#pragma unroll
        for (int rb = 0; rb < 4; ++rb) acc[rb] = *(const f32x4*)(biasLds + 64 + 16 * rb + 4 * g);
#pragma unroll
        for (int rb = 0; rb < 4; ++rb) {
            acc[rb] = MFMA(AW(2, rb, 0), bt0, acc[rb]);
            acc[rb] = MFMA(AW(2, rb, 1), bt1, acc[rb]);
        }

        // softmax accumulate: exp(relu(alpha)) = exp2(relu(alpha*log2e))
        bool ok = (tb + e) < vend;
#pragma unroll
        for (int rb = 0; rb < 4; ++rb) {
#pragma unroll
            for (int c = 0; c < 4; ++c) {
                float a = frelu(acc[rb][c]);
                float ew = ok ? exp2f(a) : 0.f;
                den[rb][c] += ew;
                num[rb][c] += ew * (bf2f(svld[rb][4 + c]) + d4[rb][c]);
            }
        }
        // svld dead -> next tile's combined {s,v} gather (4 b128)
#pragma unroll
        for (int rb = 0; rb < 4; ++rb)
            svld[rb] = *(const bf16x8*)(g1 + 64 + 32 * rb + 8 * g);

        q0A = nqA; q0B = nqB; j1 = j2;

        // node epilogue
        if (tb + 16 >= t1) {
            // reduce over 16 edge-lanes: xor1/xor2 via DPP (VALU), xor4/xor8 via shfl (DS)
#pragma unroll
            for (int rb = 0; rb < 4; ++rb)
#pragma unroll
                for (int c = 0; c < 4; ++c) {
                    float n2 = dppadd<0xB1>(num[rb][c]);   // + lane^1 (quad_perm 1,0,3,2)
                    float d2 = dppadd<0xB1>(den[rb][c]);
                    n2 = dppadd<0x4E>(n2);                 // + lane^2 (quad_perm 2,3,0,1)
                    d2 = dppadd<0x4E>(d2);
                    n2 += __shfl_xor(n2, 4);
                    d2 += __shfl_xor(d2, 4);
                    n2 += __shfl_xor(n2, 8);
                    d2 += __shfl_xor(d2, 8);
                    num[rb][c] = n2; den[rb][c] = d2;
                }
            if (e == 0) {
                unsigned short* op = obf + (size_t)node * 64;
#pragma unroll
                for (int rb = 0; rb < 4; ++rb) {
                    f32x4 ov;
#pragma unroll
                    for (int c = 0; c < 4; ++c)
                        ov[c] = num[rb][c] * __builtin_amdgcn_rcpf(den[rb][c] + 1e-16f);
                    u32x2 ow; ow[0] = pk2(ov[0], ov[1]); ow[1] = pk2(ov[2], ov[3]);
                    *(u32x2*)(op + 16 * rb + 4 * g) = ow;
                }
            }
            ++node;
            if (node < nodeEnd && node == prefN && pt1 != t1) {
                t0 = t1; t1 = pt1; vend = t0 + pdeg;
                qpA = pqpA; qpB = pqpB;
#pragma unroll
                for (int rb = 0; rb < 4; ++rb)
#pragma unroll
                    for (int c = 0; c < 4; ++c) advf[rb][c] = bf2f(padv[rb][c]);
            } else {
                while (node < nodeEnd && poff[node + 1] == t1) {
                    if (e == 0) {
                        unsigned short* op = obf + (size_t)node * 64;
#pragma unroll
                        for (int rb = 0; rb < 4; ++rb)
                            *(u32x2*)(op + 16 * rb + 4 * g) = (u32x2)0u;
                    }
                    ++node;
                }
                if (node < nodeEnd) {
                    t0 = t1; t1 = poff[node + 1];
                    vend = t0 + deg[node];
                    const unsigned short* nr2 = nad + (size_t)node * 128;
                    qpA = *(const bf16x8*)(nr2 + 8 * g);
                    qpB = *(const bf16x8*)(nr2 + 32 + 8 * g);
#pragma unroll
                    for (int rb = 0; rb < 4; ++rb) {
                        bf16x4 a = *(const bf16x4*)(nr2 + 64 + 16 * rb + 4 * g);
#pragma unroll
                        for (int c = 0; c < 4; ++c) advf[rb][c] = bf2f(a[c]);
                    }
                }
            }
            if (node < nodeEnd) {
                prefN = (node + 1 < NN) ? node + 1 : NN - 1;
                const unsigned short* pr2 = nad + (size_t)prefN * 128;
                pqpA = *(const bf16x8*)(pr2 + 8 * g);
                pqpB = *(const bf16x8*)(pr2 + 32 + 8 * g);
#pragma unroll
                for (int rb = 0; rb < 4; ++rb)
                    padv[rb] = *(const bf16x4*)(pr2 + 64 + 16 * rb + 4 * g);
                pt1 = poff[prefN + 1];
                pdeg = deg[prefN];
#pragma unroll
                for (int rb = 0; rb < 4; ++rb) { num[rb] = (f32x4)0.f; den[rb] = (f32x4)0.f; }
            }
        }
    }
#undef AW
#undef XPOSE
}

// ---- out = relu(o @ Wout + bout); o read directly as bf16 B-frags ----
__global__ void __launch_bounds__(512) k_out(const unsigned short* __restrict__ obf,
                                             const short* __restrict__ Apack,
                                             const float* __restrict__ bout,
                                             float* __restrict__ out) {
    __shared__ short Ah[4096], Al[4096];
    __shared__ float bb[64];
    {
        const int* gh = (const int*)(Apack + 3 * 4096);
        const int* gl = (const int*)(Apack + 4 * 4096);
        int* sh = (int*)Ah; int* sl = (int*)Al;
        for (int i = threadIdx.x; i < 2048; i += 512) { sh[i] = gh[i]; sl[i] = gl[i]; }
        if (threadIdx.x < 64) bb[threadIdx.x] = bout[threadIdx.x];
    }
    __syncthreads();
    int l = threadIdx.x & 63, g = l >> 4;
    int tile = blockIdx.x * 8 + (threadIdx.x >> 6);   // 0..4095
    int nbase = tile * 16;
    const unsigned short* op = obf + (size_t)(nbase + (l & 15)) * 64;
    short8 b0 = __builtin_bit_cast(short8, *(const bf16x8*)(op + 8 * g));
    short8 b1 = __builtin_bit_cast(short8, *(const bf16x8*)(op + 32 + 8 * g));
#define AF(arr, rb, s) (*(const short8*)(arr + (((rb) * 2 + (s)) * 64 + l) * 8))
    f32x4 acc[4];
#pragma unroll
    for (int rb = 0; rb < 4; ++rb) acc[rb] = *(const f32x4*)(bb + 16 * rb + 4 * g);
#pragma unroll
    for (int rb = 0; rb < 4; ++rb) {
        acc[rb] = MFMA(AF(Ah, rb, 0), b0, acc[rb]);
        acc[rb] = MFMA(AF(Ah, rb, 1), b1, acc[rb]);
        acc[rb] = MFMA(AF(Al, rb, 0), b0, acc[rb]);
        acc[rb] = MFMA(AF(Al, rb, 1), b1, acc[rb]);
    }
#undef AF
    float* outp = out + (size_t)(nbase + (l & 15)) * 64;
#pragma unroll
    for (int rb = 0; rb < 4; ++rb) {
        f32x4 r;
#pragma unroll
        for (int c = 0; c < 4; ++c) r[c] = frelu(acc[rb][c]);
        *(f32x4*)(outp + 16 * rb + 4 * g) = r;
    }
}

extern "C" void kernel_launch(void* const* d_in, const int* in_sizes, int n_in,
                              void* d_out, int out_size, void* d_ws, size_t ws_size,
                              hipStream_t stream) {
    const float* x    = (const float*)d_in[0];
    const float* pos  = (const float*)d_in[1];
    const int*   ei   = (const int*)d_in[2];
    const float* Win  = (const float*)d_in[3];
    const float* bin  = (const float*)d_in[4];
    const float* Wout = (const float*)d_in[5];
    const float* bout = (const float*)d_in[6];
    const float* Wlin = (const float*)d_in[7];
    const float* Wsrc = (const float*)d_in[8];
    const float* Wdst = (const float*)d_in[9];
    const float* P1   = (const float*)d_in[10];
    const float* p1   = (const float*)d_in[11];
    const float* P2   = (const float*)d_in[12];
    const float* p2   = (const float*)d_in[13];
    const float* A1   = (const float*)d_in[14];
    const float* a1   = (const float*)d_in[15];
    const float* A2   = (const float*)d_in[16];
    const float* a2   = (const float*)d_in[17];
    float* out = (float*)d_out;

    char* w = (char*)d_ws;
    short* Apck = (short*)w; w += 9 * 4096 * 2;
    unsigned short* obf = (unsigned short*)w; w += (size_t)NN * 64 * 2;
    unsigned short* gsv = (unsigned short*)w; w += (size_t)NN * 192 * 2;
    unsigned short* nad = (unsigned short*)w; w += (size_t)NN * 128 * 2;
    int* deg    = (int*)w; w += (size_t)NN * 4;
    int* poffp  = (int*)w; w += (size_t)(NN + 16) * 4;
    int* eslot  = (int*)w; w += (size_t)NE * 4;
    int* srtj   = (int*)w; w += (size_t)2 * NE * 4;

    k_pack<<<18 + 64, 256, 0, stream>>>(P2, A1, A2, Wout, Win, Wlin, Wdst, Wsrc,
                                        Apck, deg);
    k_front<<<1024 + 4096 + 2048, 256, 0, stream>>>(x, pos, Apck, bin, a1, P1, p1,
                                                    ei, deg, eslot, srtj, gsv, nad);
    k_scan<<<1, 1024, 0, stream>>>(deg, poffp);
    k_scatter<<<NE / 256, 256, 0, stream>>>(ei, eslot, poffp, srtj);
    k_edge<<<EW / 4, 256, 0, stream>>>(gsv, nad, poffp, deg, srtj, Apck,
                                       p2, a2, obf);
    k_out<<<512, 512, 0, stream>>>(obf, Apck, bout, out);
}

// Round 17
// 301.052 us; speedup vs baseline: 1.0585x; 1.0171x over previous
//
#include <hip/hip_runtime.h>
#include <hip/hip_bf16.h>

#define NN 65536
#define NE 1048576
#define EW 4096   // persistent waves in k_edge (1024 blocks x 4 waves = 4 blk/CU)

typedef __attribute__((ext_vector_type(8))) short short8;
typedef __attribute__((ext_vector_type(8))) unsigned short bf16x8;
typedef __attribute__((ext_vector_type(4))) unsigned short bf16x4;
typedef __attribute__((ext_vector_type(4))) float f32x4;
typedef __attribute__((ext_vector_type(4))) unsigned int u32x4;
typedef __attribute__((ext_vector_type(2))) unsigned int u32x2;
typedef __attribute__((ext_vector_type(4))) int i32x4;

__device__ __forceinline__ float lrelu(float x) { return fmaxf(x, 0.01f * x); }
__device__ __forceinline__ float frelu(float x) { return fmaxf(x, 0.f); }
__device__ __forceinline__ short f2bf(float f) {
    __hip_bfloat16 h = __float2bfloat16(f);
    return *reinterpret_cast<short*>(&h);
}
__device__ __forceinline__ float bf2f(unsigned short s) {
    return __uint_as_float(((unsigned)s) << 16);
}
// single-instruction packed f32x2 -> bf16x2 (RNE), lo in low half
__device__ __forceinline__ unsigned pk2(float lo, float hi) {
    unsigned r;
    asm("v_cvt_pk_bf16_f32 %0, %1, %2" : "=v"(r) : "v"(lo), "v"(hi));
    return r;
}
__device__ __forceinline__ void st4(unsigned short* p, f32x4 v) {
    u32x2 w; w[0] = pk2(v[0], v[1]); w[1] = pk2(v[2], v[3]);
    *(u32x2*)p = w;
}
// DPP quad-perm add: x + lane_xor_m(x) for m=1 (ctrl 0xB1) / m=2 (ctrl 0x4E); VALU-only
template <int CTRL>
__device__ __forceinline__ float dppadd(float x) {
    int sh = __builtin_amdgcn_update_dpp(0, __float_as_int(x), CTRL, 0xF, 0xF, true);
    return x + __int_as_float(sh);
}

// ---- pack MFMA A-frags: 0=P2 1=A1 2=A2(x log2e) 3=Wout_hi 4=Wout_lo 5=Win 6=Wlin
//      7=Wda(=Wdst@A1) 8=Wsa(=Wsrc@A1); blocks >=18 zero deg ----
__global__ void k_pack(const float* __restrict__ P2, const float* __restrict__ A1,
                       const float* __restrict__ A2, const float* __restrict__ Wout,
                       const float* __restrict__ Win, const float* __restrict__ Wlin,
                       const float* __restrict__ Wdst, const float* __restrict__ Wsrc,
                       short* __restrict__ Apack, int* __restrict__ deg) {
    if (blockIdx.x >= 18) {            // deg zeroing: 64 blocks x 256 x 4 ints
        int i = (blockIdx.x - 18) * 1024 + threadIdx.x * 4;
        *(i32x4*)(deg + i) = (i32x4)0;
        return;
    }
    int idx = blockIdx.x * 256 + threadIdx.x;   // fid*512 + (rb*2+s)*64 + l
    if (idx >= 9 * 512) return;
    int l = idx & 63, s = (idx >> 6) & 1, rb = (idx >> 7) & 3, fid = idx >> 9;
    const float* Wt[7] = {P2, A1, A2, Wout, Wout, Win, Wlin};
    bool lo = (fid == 4);
#pragma unroll
    for (int b = 0; b < 8; ++b) {
        int in = 32 * s + 8 * (l >> 4) + b;
        int out = 16 * rb + (l & 15);
        float w;
        if (fid >= 7) {
            const float* Wsel = (fid == 7) ? Wdst : Wsrc;
            float acc = 0.f;
            for (int k = 0; k < 64; ++k) acc += Wsel[in * 64 + k] * A1[k * 64 + out];
            w = acc;
        } else {
            w = Wt[fid][in * 64 + out];
            if (fid == 2) w *= 1.44269504088896f;   // fold exp->exp2
        }
        short hi = f2bf(w);
        Apack[idx * 8 + b] = lo ? f2bf(w - bf2f((unsigned short)hi)) : hi;
    }
}

#define MFMA(a, b, c) __builtin_amdgcn_mfma_f32_16x16x32_bf16(a, b, c, 0, 0, 0)

// ---- fused front: node MFMA (768, grid-stride) || hist+slot (4096) || srtj zero (2048)
// gsv row (192 bf16): [0..63]=q ; [64+32rb+8g+0..3]=s ; [64+32rb+8g+4..7]=v
__global__ void __launch_bounds__(256) k_front(
    const float* __restrict__ x, const float* __restrict__ pos,
    const short* __restrict__ Apack,
    const float* __restrict__ bin, const float* __restrict__ a1,
    const float* __restrict__ P1, const float* __restrict__ p1,
    const int* __restrict__ ei, int* __restrict__ deg, int* __restrict__ eslot,
    int* __restrict__ srtj,
    unsigned short* __restrict__ gsv, unsigned short* __restrict__ nad) {
    if (blockIdx.x >= 4864) {          // srtj zeroing: 2048 blocks x 256 x 4 ints
        int i = (blockIdx.x - 4864) * 1024 + threadIdx.x * 4;
        *(i32x4*)(srtj + i) = (i32x4)0;
        return;
    }
    if (blockIdx.x >= 768) {           // histogram + slot record
        int e = (blockIdx.x - 768) * 256 + threadIdx.x;
        eslot[e] = atomicAdd(&deg[ei[NE + e]], 1);
        return;
    }
    __shared__ short AW2[4 * 4096];   // fids 5..8: Win, Wlin, Wda, Wsa
    __shared__ float cb[384];         // [0]bin [64]a1 [128]p1 [192..384]P1
    __shared__ unsigned stg[4][768];  // per-wave transpose stage: 64 lanes x 12 words
    {
        const int* gA = (const int*)(Apack + 5 * 4096);
        int* sA = (int*)AW2;
        for (int i = threadIdx.x; i < 8192; i += 256) sA[i] = gA[i];
        if (threadIdx.x < 64) {
            cb[threadIdx.x] = bin[threadIdx.x];
            cb[64 + threadIdx.x] = a1[threadIdx.x];
            cb[128 + threadIdx.x] = p1[threadIdx.x];
        }
        if (threadIdx.x < 192) cb[192 + threadIdx.x] = P1[threadIdx.x];
    }
    __syncthreads();
    int l = threadIdx.x & 63, g = l >> 4, e = l & 15;
    // destination-centric transpose stage addressing (stride 12 words = 48B)
    unsigned* sbw = stg[threadIdx.x >> 6];
    int wbase = (l & 16) ? 2 : 0;
    int tdst1 = 16 * ((l >= 32) ? 1 : 0) + e;
    unsigned* wp0 = sbw + tdst1 * 12 + wbase;
    unsigned* wp1 = wp0 + 4;
    unsigned* wp2 = sbw + (tdst1 + 32) * 12 + wbase;
    unsigned* wp3 = wp2 + 4;
    const unsigned* rp0 = sbw + l * 12;
    const unsigned* rp1 = rp0 + 4;
#define AF2(f, rb, s) (*(const short8*)(AW2 + ((((f) * 4 + (rb)) * 2 + (s)) * 64 + l) * 8))
#define XPOSE(cA, cB, f0, f1)                                              \
    {                                                                      \
        u32x2 _a; _a[0] = cA[0]; _a[1] = cA[1]; *(u32x2*)wp0 = _a;         \
        _a[0] = cB[0]; _a[1] = cB[1]; *(u32x2*)wp1 = _a;                   \
        _a[0] = cA[2]; _a[1] = cA[3]; *(u32x2*)wp2 = _a;                   \
        _a[0] = cB[2]; _a[1] = cB[3]; *(u32x2*)wp3 = _a;                   \
        f0 = __builtin_bit_cast(short8, *(const u32x4*)rp0);               \
        f1 = __builtin_bit_cast(short8, *(const u32x4*)rp1);               \
    }
    int wv = blockIdx.x * 4 + (threadIdx.x >> 6);   // 0..3071
    for (int tile = wv; tile < 4096; tile += 3072) {
        int n = tile * 16 + e;
        float p0 = pos[n * 3 + 0], p1v = pos[n * 3 + 1], p2v = pos[n * 3 + 2];
        const float* xr = x + (size_t)n * 64 + 8 * g;
        f32x4 x00 = *(const f32x4*)(xr), x01 = *(const f32x4*)(xr + 4);
        f32x4 x10 = *(const f32x4*)(xr + 32), x11 = *(const f32x4*)(xr + 36);
        short8 xh[2], xl[2];
#pragma unroll
        for (int b = 0; b < 4; ++b) {
            float f;
            f = x00[b]; xh[0][b] = f2bf(f);     xl[0][b] = f2bf(f - bf2f((unsigned short)xh[0][b]));
            f = x01[b]; xh[0][b + 4] = f2bf(f); xl[0][b + 4] = f2bf(f - bf2f((unsigned short)xh[0][b + 4]));
            f = x10[b]; xh[1][b] = f2bf(f);     xl[1][b] = f2bf(f - bf2f((unsigned short)xh[1][b]));
            f = x11[b]; xh[1][b + 4] = f2bf(f); xl[1][b + 4] = f2bf(f - bf2f((unsigned short)xh[1][b + 4]));
        }
        // h = relu(Win^T x + bin)
        f32x4 acc[4];
#pragma unroll
        for (int rb = 0; rb < 4; ++rb) acc[rb] = *(const f32x4*)(cb + 16 * rb + 4 * g);
#pragma unroll
        for (int rb = 0; rb < 4; ++rb) {
            acc[rb] = MFMA(AF2(0, rb, 0), xh[0], acc[rb]);
            acc[rb] = MFMA(AF2(0, rb, 1), xh[1], acc[rb]);
            acc[rb] = MFMA(AF2(0, rb, 0), xl[0], acc[rb]);
            acc[rb] = MFMA(AF2(0, rb, 1), xl[1], acc[rb]);
        }
        f32x4 hv[4], res[4];
#pragma unroll
        for (int rb = 0; rb < 4; ++rb)
#pragma unroll
            for (int c = 0; c < 4; ++c) {
                float f = frelu(acc[rb][c]);
                hv[rb][c] = f;
                res[rb][c] = f - bf2f((unsigned short)f2bf(f));
            }
        u32x4 HhA, HhB, HlA, HlB;
        HhA[0] = pk2(hv[0][0], hv[0][1]); HhA[1] = pk2(hv[0][2], hv[0][3]);
        HhA[2] = pk2(hv[1][0], hv[1][1]); HhA[3] = pk2(hv[1][2], hv[1][3]);
        HhB[0] = pk2(hv[2][0], hv[2][1]); HhB[1] = pk2(hv[2][2], hv[2][3]);
        HhB[2] = pk2(hv[3][0], hv[3][1]); HhB[3] = pk2(hv[3][2], hv[3][3]);
        HlA[0] = pk2(res[0][0], res[0][1]); HlA[1] = pk2(res[0][2], res[0][3]);
        HlA[2] = pk2(res[1][0], res[1][1]); HlA[3] = pk2(res[1][2], res[1][3]);
        HlB[0] = pk2(res[2][0], res[2][1]); HlB[1] = pk2(res[2][2], res[2][3]);
        HlB[2] = pk2(res[3][0], res[3][1]); HlB[3] = pk2(res[3][2], res[3][3]);
        short8 bhh0, bhh1, bhl0, bhl1;
        XPOSE(HhA, HhB, bhh0, bhh1);
        XPOSE(HlA, HlB, bhl0, bhl1);

        unsigned short* gr = gsv + (size_t)n * 192;
        unsigned short* nr = nad + (size_t)n * 128;
        f32x4 vres[4];
#pragma unroll
        for (int rb = 0; rb < 4; ++rb) {   // v = h @ Wlin (regs)
            f32x4 a = (f32x4)0.f;
            a = MFMA(AF2(1, rb, 0), bhh0, a);
            a = MFMA(AF2(1, rb, 1), bhh1, a);
            a = MFMA(AF2(1, rb, 0), bhl0, a);
            a = MFMA(AF2(1, rb, 1), bhl1, a);
            vres[rb] = a;
        }
#pragma unroll
        for (int rb = 0; rb < 4; ++rb) {   // s = h @ Wsa; write combined {s,v} b128
            f32x4 a = (f32x4)0.f;
            a = MFMA(AF2(3, rb, 0), bhh0, a);
            a = MFMA(AF2(3, rb, 1), bhh1, a);
            a = MFMA(AF2(3, rb, 0), bhl0, a);
            a = MFMA(AF2(3, rb, 1), bhl1, a);
            u32x4 wv4;
            wv4[0] = pk2(a[0], a[1]); wv4[1] = pk2(a[2], a[3]);
            wv4[2] = pk2(vres[rb][0], vres[rb][1]); wv4[3] = pk2(vres[rb][2], vres[rb][3]);
            *(u32x4*)(gr + 64 + 32 * rb + 8 * g) = wv4;
        }
#pragma unroll
        for (int rb = 0; rb < 4; ++rb) {   // ad = h @ Wda + a1
            f32x4 a = *(const f32x4*)(cb + 64 + 16 * rb + 4 * g);
            a = MFMA(AF2(2, rb, 0), bhh0, a);
            a = MFMA(AF2(2, rb, 1), bhh1, a);
            a = MFMA(AF2(2, rb, 0), bhl0, a);
            a = MFMA(AF2(2, rb, 1), bhl1, a);
            st4(nr + 64 + 16 * rb + 4 * g, a);
        }
#pragma unroll
        for (int rb = 0; rb < 4; ++rb) {   // q = pos @ P1 ; qp = q + p1
            f32x4 qv, qpv;
#pragma unroll
            for (int c = 0; c < 4; ++c) {
                int ch = 16 * rb + 4 * g + c;
                float q = p0 * cb[192 + ch] + p1v * cb[256 + ch] + p2v * cb[320 + ch];
                qv[c] = q; qpv[c] = q + cb[128 + ch];
            }
            st4(gr + 16 * rb + 4 * g, qv);
            st4(nr + 16 * rb + 4 * g, qpv);
        }
    }
#undef AF2
#undef XPOSE
}

// pure scan (wstart computed in k_edge; vectorized int4 loads/stores)
__global__ void __launch_bounds__(1024) k_scan(const int* __restrict__ deg,
                                               int* __restrict__ poff) {
    __shared__ int part[1024];
    int t = threadIdx.x;
    int base = t * 64;
    int s = 0;
#pragma unroll
    for (int r = 0; r < 64; r += 4) {
        i32x4 d = *(const i32x4*)(deg + base + r);
        s += ((d[0] + 15) & ~15) + ((d[1] + 15) & ~15)
           + ((d[2] + 15) & ~15) + ((d[3] + 15) & ~15);
    }
    part[t] = s;
    __syncthreads();
    int v = s;
    for (int off = 1; off < 1024; off <<= 1) {
        int add = (t >= off) ? part[t - off] : 0;
        __syncthreads();
        v += add; part[t] = v;
        __syncthreads();
    }
    int run = v - s;   // exclusive prefix
#pragma unroll
    for (int r = 0; r < 64; r += 4) {
        i32x4 d = *(const i32x4*)(deg + base + r);
        i32x4 po;
#pragma unroll
        for (int k = 0; k < 4; ++k) { po[k] = run; run += (d[k] + 15) & ~15; }
        *(i32x4*)(poff + base + r) = po;
    }
    if (t == 1023) poff[NN] = run;
}

// ---- atomic-free scatter using recorded slots ----
__global__ void k_scatter(const int* __restrict__ ei, const int* __restrict__ eslot,
                          const int* __restrict__ poff, int* __restrict__ srtj) {
    int e = blockIdx.x * 256 + threadIdx.x;
    int i = ei[NE + e];
    srtj[poff[i] + eslot[e]] = ei[e] * 192;   // pre-scaled element offset into gsv
}

// ---- persistent fused edge MLP; self-partition, LDS transpose, prefetch rotation ----
__global__ void __launch_bounds__(256) k_edge(
    const unsigned short* __restrict__ gsv, const unsigned short* __restrict__ nad,
    const int* __restrict__ poff, const int* __restrict__ deg,
    const int* __restrict__ srtj, const short* __restrict__ Apack,
    const float* __restrict__ p2b, const float* __restrict__ a2b,
    unsigned short* __restrict__ obf) {
    __shared__ short AwLds[12288];     // 3 layers x 4 rb x 2 s x 64 lanes x 8 bf16
    __shared__ float biasLds[128];     // [0]p2b [64]a2b(x log2e)
    __shared__ unsigned stg[4][768];   // per-wave transpose stage: 64 lanes x 12 words
    {
        const int* gA = (const int*)Apack;
        int* sA = (int*)AwLds;
        for (int i = threadIdx.x; i < 6144; i += 256) sA[i] = gA[i];
        if (threadIdx.x < 64) {
            biasLds[threadIdx.x] = p2b[threadIdx.x];
            biasLds[64 + threadIdx.x] = a2b[threadIdx.x] * 1.44269504088896f;
        }
    }

    int l = threadIdx.x & 63;
    int g = l >> 4, e = l & 15;
    int w = blockIdx.x * 4 + (threadIdx.x >> 6);   // 0..EW-1

    // self-computed tile-balanced partition (overlaps with LDS staging above)
    int tot = poff[NN];
    int node, nodeEnd;
    {
        long long t1l = (long long)w * tot;
        int tgt = (int)(t1l / EW);
        int lo = 0, hi2 = NN;
        while (lo < hi2) { int mid = (lo + hi2) >> 1; if (poff[mid] < tgt) lo = mid + 1; else hi2 = mid; }
        node = lo;
        if (w + 1 == EW) nodeEnd = NN;
        else {
            int tgt2 = (int)((t1l + tot) / EW);
            lo = 0; hi2 = NN;
            while (lo < hi2) { int mid = (lo + hi2) >> 1; if (poff[mid] < tgt2) lo = mid + 1; else hi2 = mid; }
            nodeEnd = lo;
        }
    }
    __syncthreads();

    // destination-centric transpose stage addressing (stride 12 words = 48B)
    unsigned* sbw = stg[threadIdx.x >> 6];
    int wbase = (l & 16) ? 2 : 0;
    int tdst1 = 16 * ((l >= 32) ? 1 : 0) + e;
    unsigned* wp0 = sbw + tdst1 * 12 + wbase;
    unsigned* wp1 = wp0 + 4;
    unsigned* wp2 = sbw + (tdst1 + 32) * 12 + wbase;
    unsigned* wp3 = wp2 + 4;
    const unsigned* rp0 = sbw + l * 12;
    const unsigned* rp1 = rp0 + 4;

#define AW(L, rb, s) (*(const short8*)(AwLds + ((((L) * 4 + (rb)) * 2 + (s)) * 64 + l) * 8))
#define XPOSE(cA, cB, f0, f1)                                              \
    {                                                                      \
        u32x2 _a; _a[0] = cA[0]; _a[1] = cA[1]; *(u32x2*)wp0 = _a;         \
        _a[0] = cB[0]; _a[1] = cB[1]; *(u32x2*)wp1 = _a;                   \
        _a[0] = cA[2]; _a[1] = cA[3]; *(u32x2*)wp2 = _a;                   \
        _a[0] = cB[2]; _a[1] = cB[3]; *(u32x2*)wp3 = _a;                   \
        f0 = __builtin_bit_cast(short8, *(const u32x4*)rp0);               \
        f1 = __builtin_bit_cast(short8, *(const u32x4*)rp1);               \
    }

    while (node < nodeEnd && poff[node + 1] == poff[node]) {
        if (e == 0) {
            unsigned short* op = obf + (size_t)node * 64;
#pragma unroll
            for (int rb = 0; rb < 4; ++rb) *(u32x2*)(op + 16 * rb + 4 * g) = (u32x2)0u;
        }
        ++node;
    }
    if (node >= nodeEnd) return;

    int t0 = poff[node], t1 = poff[node + 1];
    int vend = t0 + deg[node];
    int tendW = poff[nodeEnd];

    // current node constants (adv pre-unpacked to f32)
    const unsigned short* nr = nad + (size_t)node * 128;
    bf16x8 qpA = *(const bf16x8*)(nr + 8 * g);
    bf16x8 qpB = *(const bf16x8*)(nr + 32 + 8 * g);
    f32x4 advf[4];
#pragma unroll
    for (int rb = 0; rb < 4; ++rb) {
        bf16x4 a = *(const bf16x4*)(nr + 64 + 16 * rb + 4 * g);
#pragma unroll
        for (int c = 0; c < 4; ++c) advf[rb][c] = bf2f(a[c]);
    }

    // next-node prefetch state (kept packed)
    int prefN = (node + 1 < NN) ? node + 1 : NN - 1;
    const unsigned short* pr = nad + (size_t)prefN * 128;
    bf16x8 pqpA = *(const bf16x8*)(pr + 8 * g);
    bf16x8 pqpB = *(const bf16x8*)(pr + 32 + 8 * g);
    bf16x4 padv[4];
#pragma unroll
    for (int rb = 0; rb < 4; ++rb)
        padv[rb] = *(const bf16x4*)(pr + 64 + 16 * rb + 4 * g);
    int pt1 = poff[prefN + 1];
    int pdeg = deg[prefN];

    f32x4 num[4], den[4];
#pragma unroll
    for (int rb = 0; rb < 4; ++rb) { num[rb] = (f32x4)0.f; den[rb] = (f32x4)0.f; }

    // edge pipeline prologue
    int j1 = srtj[t0 + 16 + e];
    const unsigned short* g0 = gsv + srtj[t0 + e];
    bf16x8 q0A = *(const bf16x8*)(g0 + 8 * g);
    bf16x8 q0B = *(const bf16x8*)(g0 + 32 + 8 * g);
    bf16x8 svld[4];   // [0..3]=s, [4..7]=v per rb
#pragma unroll
    for (int rb = 0; rb < 4; ++rb)
        svld[rb] = *(const bf16x8*)(g0 + 64 + 32 * rb + 8 * g);

    for (int tb = t0; tb < tendW; tb += 16) {
        int j2 = srtj[tb + 32 + e];                      // 2-ahead (sequential)
        const unsigned short* g1 = gsv + j1;             // 1-ahead gather
        bf16x8 nqA = *(const bf16x8*)(g1 + 8 * g);
        bf16x8 nqB = *(const bf16x8*)(g1 + 32 + 8 * g);

        // u = lrelu(qp_i - q_j) -> bf16 B-frags
        u32x4 buA, buB;
#pragma unroll
        for (int p = 0; p < 4; ++p) {
            float u0 = lrelu(bf2f(qpA[2 * p]) - bf2f(q0A[2 * p]));
            float u1 = lrelu(bf2f(qpA[2 * p + 1]) - bf2f(q0A[2 * p + 1]));
            buA[p] = pk2(u0, u1);
            u0 = lrelu(bf2f(qpB[2 * p]) - bf2f(q0B[2 * p]));
            u1 = lrelu(bf2f(qpB[2 * p + 1]) - bf2f(q0B[2 * p + 1]));
            buB[p] = pk2(u0, u1);
        }
        short8 bu0 = __builtin_bit_cast(short8, buA);
        short8 bu1 = __builtin_bit_cast(short8, buB);

        // layer 1: d^T = P2^T u^T + p2b
        f32x4 acc[4];
#pragma unroll
        for (int rb = 0; rb < 4; ++rb) acc[rb] = *(const f32x4*)(biasLds + 16 * rb + 4 * g);
#pragma unroll
        for (int rb = 0; rb < 4; ++rb) {
            acc[rb] = MFMA(AW(0, rb, 0), bu0, acc[rb]);
            acc[rb] = MFMA(AW(0, rb, 1), bu1, acc[rb]);
        }
        f32x4 d4[4];
#pragma unroll
        for (int rb = 0; rb < 4; ++rb)
#pragma unroll
            for (int c = 0; c < 4; ++c) d4[rb][c] = lrelu(acc[rb][c]);
        u32x4 dA, dB;
        dA[0] = pk2(d4[0][0], d4[0][1]); dA[1] = pk2(d4[0][2], d4[0][3]);
        dA[2] = pk2(d4[1][0], d4[1][1]); dA[3] = pk2(d4[1][2], d4[1][3]);
        dB[0] = pk2(d4[2][0], d4[2][1]); dB[1] = pk2(d4[2][2], d4[2][3]);
        dB[2] = pk2(d4[3][0], d4[3][1]); dB[3] = pk2(d4[3][2], d4[3][3]);
        short8 bd0, bd1;
        XPOSE(dA, dB, bd0, bd1);

        // layer 2 init: adv_i - as1_j (s = svld[rb][0..3])
#pragma unroll
        for (int rb = 0; rb < 4; ++rb) {
            f32x4 t;
#pragma unroll
            for (int c = 0; c < 4; ++c) t[c] = advf[rb][c] - bf2f(svld[rb][c]);
            acc[rb] = t;
        }
#pragma unroll
        for (int rb = 0; rb < 4; ++rb) {
            acc[rb] = MFMA(AW(1, rb, 0), bd0, acc[rb]);
            acc[rb] = MFMA(AW(1, rb, 1), bd1, acc[rb]);
        }
        u32x4 tA, tB;
        tA[0] = pk2(frelu(acc[0][0]), frelu(acc[0][1]));
        tA[1] = pk2(frelu(acc[0][2]), frelu(acc[0][3]));
        tA[2] = pk2(frelu(acc[1][0]), frelu(acc[1][1]));
        tA[3] = pk2(frelu(acc[1][2]), frelu(acc[1][3]));
        tB[0] = pk2(frelu(acc[2][0]), frelu(acc[2][1]));
        tB[1] = pk2(frelu(acc[2][2]), frelu(acc[2][3]));
        tB[2] = pk2(frelu(acc[3][0]), frelu(acc[3][1]));
        tB[3] = pk2(frelu(acc[3][2]), frelu(acc[3][3]));
        short8 bt0, bt1;
        XPOSE(tA, tB, bt0, bt1);

        // layer 3: alpha2^T = (A2 log2e)^T t^T + a2 log2e
#pragma unroll
        for (int rb = 0; rb < 4; ++rb) acc[rb] = *(const f32x4*)(biasLds + 64 + 16 * rb + 4 * g);
#pragma unroll
        for (int rb = 0; rb < 4; ++rb) {
            acc[rb] = MFMA(AW(2, rb, 0), bt0, acc[rb]);
            acc[rb] = MFMA(AW(2, rb, 1), bt1, acc[rb]);
        }

        // softmax accumulate: exp(relu(alpha)) = exp2(relu(alpha*log2e))
        bool ok = (tb + e) < vend;
#pragma unroll
        for (int rb = 0; rb < 4; ++rb) {
#pragma unroll
            for (int c = 0; c < 4; ++c) {
                float a = frelu(acc[rb][c]);
                float ew = ok ? exp2f(a) : 0.f;
                den[rb][c] += ew;
                num[rb][c] += ew * (bf2f(svld[rb][4 + c]) + d4[rb][c]);
            }
        }
        // svld dead -> next tile's combined {s,v} gather (4 b128)
#pragma unroll
        for (int rb = 0; rb < 4; ++rb)
            svld[rb] = *(const bf16x8*)(g1 + 64 + 32 * rb + 8 * g);

        q0A = nqA; q0B = nqB; j1 = j2;

        // node epilogue
        if (tb + 16 >= t1) {
            // reduce over 16 edge-lanes: xor1/xor2 via DPP (VALU), xor4/xor8 via shfl (DS)
#pragma unroll
            for (int rb = 0; rb < 4; ++rb)
#pragma unroll
                for (int c = 0; c < 4; ++c) {
                    float n2 = dppadd<0xB1>(num[rb][c]);   // + lane^1 (quad_perm 1,0,3,2)
                    float d2 = dppadd<0xB1>(den[rb][c]);
                    n2 = dppadd<0x4E>(n2);                 // + lane^2 (quad_perm 2,3,0,1)
                    d2 = dppadd<0x4E>(d2);
                    n2 += __shfl_xor(n2, 4);
                    d2 += __shfl_xor(d2, 4);
                    n2 += __shfl_xor(n2, 8);
                    d2 += __shfl_xor(d2, 8);
                    num[rb][c] = n2; den[rb][c] = d2;
                }
            if (e == 0) {
                unsigned short* op = obf + (size_t)node * 64;
#pragma unroll
                for (int rb = 0; rb < 4; ++rb) {
                    f32x4 ov;
#pragma unroll
                    for (int c = 0; c < 4; ++c)
                        ov[c] = num[rb][c] * __builtin_amdgcn_rcpf(den[rb][c] + 1e-16f);
                    u32x2 ow; ow[0] = pk2(ov[0], ov[1]); ow[1] = pk2(ov[2], ov[3]);
                    *(u32x2*)(op + 16 * rb + 4 * g) = ow;
                }
            }
            ++node;
            if (node < nodeEnd && node == prefN && pt1 != t1) {
                t0 = t1; t1 = pt1; vend = t0 + pdeg;
                qpA = pqpA; qpB = pqpB;
#pragma unroll
                for (int rb = 0; rb < 4; ++rb)
#pragma unroll
                    for (int c = 0; c < 4; ++c) advf[rb][c] = bf2f(padv[rb][c]);
            } else {
                while (node < nodeEnd && poff[node + 1] == t1) {
                    if (e == 0) {
                        unsigned short* op = obf + (size_t)node * 64;
#pragma unroll
                        for (int rb = 0; rb < 4; ++rb)
                            *(u32x2*)(op + 16 * rb + 4 * g) = (u32x2)0u;
                    }
                    ++node;
                }
                if (node < nodeEnd) {
                    t0 = t1; t1 = poff[node + 1];
                    vend = t0 + deg[node];
                    const unsigned short* nr2 = nad + (size_t)node * 128;
                    qpA = *(const bf16x8*)(nr2 + 8 * g);
                    qpB = *(const bf16x8*)(nr2 + 32 + 8 * g);
#pragma unroll
                    for (int rb = 0; rb < 4; ++rb) {
                        bf16x4 a = *(const bf16x4*)(nr2 + 64 + 16 * rb + 4 * g);
#pragma unroll
                        for (int c = 0; c < 4; ++c) advf[rb][c] = bf2f(a[c]);
                    }
                }
            }
            if (node < nodeEnd) {
                prefN = (node + 1 < NN) ? node + 1 : NN - 1;
                const unsigned short* pr2 = nad + (size_t)prefN * 128;
                pqpA = *(const bf16x8*)(pr2 + 8 * g);
                pqpB = *(const bf16x8*)(pr2 + 32 + 8 * g);
#pragma unroll
                for (int rb = 0; rb < 4; ++rb)
                    padv[rb] = *(const bf16x4*)(pr2 + 64 + 16 * rb + 4 * g);
                pt1 = poff[prefN + 1];
                pdeg = deg[prefN];
#pragma unroll
                for (int rb = 0; rb < 4; ++rb) { num[rb] = (f32x4)0.f; den[rb] = (f32x4)0.f; }
            }
        }
    }
#undef AW
#undef XPOSE
}

// ---- out = relu(o @ Wout + bout); o read directly as bf16 B-frags ----
__global__ void __launch_bounds__(512) k_out(const unsigned short* __restrict__ obf,
                                             const short* __restrict__ Apack,
                                             const float* __restrict__ bout,
                                             float* __restrict__ out) {
    __shared__ short Ah[4096], Al[4096];
    __shared__ float bb[64];
    {
        const int* gh = (const int*)(Apack + 3 * 4096);
        const int* gl = (const int*)(Apack + 4 * 4096);
        int* sh = (int*)Ah; int* sl = (int*)Al;
        for (int i = threadIdx.x; i < 2048; i += 512) { sh[i] = gh[i]; sl[i] = gl[i]; }
        if (threadIdx.x < 64) bb[threadIdx.x] = bout[threadIdx.x];
    }
    __syncthreads();
    int l = threadIdx.x & 63, g = l >> 4;
    int tile = blockIdx.x * 8 + (threadIdx.x >> 6);   // 0..4095
    int nbase = tile * 16;
    const unsigned short* op = obf + (size_t)(nbase + (l & 15)) * 64;
    short8 b0 = __builtin_bit_cast(short8, *(const bf16x8*)(op + 8 * g));
    short8 b1 = __builtin_bit_cast(short8, *(const bf16x8*)(op + 32 + 8 * g));
#define AF(arr, rb, s) (*(const short8*)(arr + (((rb) * 2 + (s)) * 64 + l) * 8))
    f32x4 acc[4];
#pragma unroll
    for (int rb = 0; rb < 4; ++rb) acc[rb] = *(const f32x4*)(bb + 16 * rb + 4 * g);
#pragma unroll
    for (int rb = 0; rb < 4; ++rb) {
        acc[rb] = MFMA(AF(Ah, rb, 0), b0, acc[rb]);
        acc[rb] = MFMA(AF(Ah, rb, 1), b1, acc[rb]);
        acc[rb] = MFMA(AF(Al, rb, 0), b0, acc[rb]);
        acc[rb] = MFMA(AF(Al, rb, 1), b1, acc[rb]);
    }
#undef AF
    float* outp = out + (size_t)(nbase + (l & 15)) * 64;
#pragma unroll
    for (int rb = 0; rb < 4; ++rb) {
        f32x4 r;
#pragma unroll
        for (int c = 0; c < 4; ++c) r[c] = frelu(acc[rb][c]);
        *(f32x4*)(outp + 16 * rb + 4 * g) = r;
    }
}

extern "C" void kernel_launch(void* const* d_in, const int* in_sizes, int n_in,
                              void* d_out, int out_size, void* d_ws, size_t ws_size,
                              hipStream_t stream) {
    const float* x    = (const float*)d_in[0];
    const float* pos  = (const float*)d_in[1];
    const int*   ei   = (const int*)d_in[2];
    const float* Win  = (const float*)d_in[3];
    const float* bin  = (const float*)d_in[4];
    const float* Wout = (const float*)d_in[5];
    const float* bout = (const float*)d_in[6];
    const float* Wlin = (const float*)d_in[7];
    const float* Wsrc = (const float*)d_in[8];
    const float* Wdst = (const float*)d_in[9];
    const float* P1   = (const float*)d_in[10];
    const float* p1   = (const float*)d_in[11];
    const float* P2   = (const float*)d_in[12];
    const float* p2   = (const float*)d_in[13];
    const float* A1   = (const float*)d_in[14];
    const float* a1   = (const float*)d_in[15];
    const float* A2   = (const float*)d_in[16];
    const float* a2   = (const float*)d_in[17];
    float* out = (float*)d_out;

    char* w = (char*)d_ws;
    short* Apck = (short*)w; w += 9 * 4096 * 2;
    unsigned short* obf = (unsigned short*)w; w += (size_t)NN * 64 * 2;
    unsigned short* gsv = (unsigned short*)w; w += (size_t)NN * 192 * 2;
    unsigned short* nad = (unsigned short*)w; w += (size_t)NN * 128 * 2;
    int* deg    = (int*)w; w += (size_t)NN * 4;
    int* poffp  = (int*)w; w += (size_t)(NN + 16) * 4;
    int* eslot  = (int*)w; w += (size_t)NE * 4;
    int* srtj   = (int*)w; w += (size_t)2 * NE * 4;

    k_pack<<<18 + 64, 256, 0, stream>>>(P2, A1, A2, Wout, Win, Wlin, Wdst, Wsrc,
                                        Apck, deg);
    k_front<<<768 + 4096 + 2048, 256, 0, stream>>>(x, pos, Apck, bin, a1, P1, p1,
                                                   ei, deg, eslot, srtj, gsv, nad);
    k_scan<<<1, 1024, 0, stream>>>(deg, poffp);
    k_scatter<<<NE / 256, 256, 0, stream>>>(ei, eslot, poffp, srtj);
    k_edge<<<EW / 4, 256, 0, stream>>>(gsv, nad, poffp, deg, srtj, Apck,
                                       p2, a2, obf);
    k_out<<<512, 512, 0, stream>>>(obf, Apck, bout, out);
}

// Round 18
// 299.546 us; speedup vs baseline: 1.0638x; 1.0050x over previous
//
#include <hip/hip_runtime.h>
#include <hip/hip_bf16.h>

#define NN 65536
#define NE 1048576
#define EW 4096   // persistent waves in k_edge (1024 blocks x 4 waves = 4 blk/CU)

typedef __attribute__((ext_vector_type(8))) short short8;
typedef __attribute__((ext_vector_type(8))) unsigned short bf16x8;
typedef __attribute__((ext_vector_type(4))) unsigned short bf16x4;
typedef __attribute__((ext_vector_type(4))) float f32x4;
typedef __attribute__((ext_vector_type(4))) unsigned int u32x4;
typedef __attribute__((ext_vector_type(2))) unsigned int u32x2;
typedef __attribute__((ext_vector_type(4))) int i32x4;

__device__ __forceinline__ float lrelu(float x) { return fmaxf(x, 0.01f * x); }
__device__ __forceinline__ float frelu(float x) { return fmaxf(x, 0.f); }
__device__ __forceinline__ short f2bf(float f) {
    __hip_bfloat16 h = __float2bfloat16(f);
    return *reinterpret_cast<short*>(&h);
}
__device__ __forceinline__ float bf2f(unsigned short s) {
    return __uint_as_float(((unsigned)s) << 16);
}
// single-instruction packed f32x2 -> bf16x2 (RNE), lo in low half
__device__ __forceinline__ unsigned pk2(float lo, float hi) {
    unsigned r;
    asm("v_cvt_pk_bf16_f32 %0, %1, %2" : "=v"(r) : "v"(lo), "v"(hi));
    return r;
}
__device__ __forceinline__ void st4(unsigned short* p, f32x4 v) {
    u32x2 w; w[0] = pk2(v[0], v[1]); w[1] = pk2(v[2], v[3]);
    *(u32x2*)p = w;
}
// DPP quad-perm add: x + lane_xor_m(x) for m=1 (ctrl 0xB1) / m=2 (ctrl 0x4E); VALU-only
template <int CTRL>
__device__ __forceinline__ float dppadd(float x) {
    int sh = __builtin_amdgcn_update_dpp(0, __float_as_int(x), CTRL, 0xF, 0xF, true);
    return x + __int_as_float(sh);
}

// ---- pack MFMA A-frags: 0=P2 1=A1 2=A2(x log2e) 3=Wout_hi 4=Wout_lo 5=Win 6=Wlin
//      7=Wda(=Wdst@A1) 8=Wsa(=Wsrc@A1); blocks >=18 zero deg ----
__global__ void k_pack(const float* __restrict__ P2, const float* __restrict__ A1,
                       const float* __restrict__ A2, const float* __restrict__ Wout,
                       const float* __restrict__ Win, const float* __restrict__ Wlin,
                       const float* __restrict__ Wdst, const float* __restrict__ Wsrc,
                       short* __restrict__ Apack, int* __restrict__ deg) {
    if (blockIdx.x >= 18) {            // deg zeroing: 64 blocks x 256 x 4 ints
        int i = (blockIdx.x - 18) * 1024 + threadIdx.x * 4;
        *(i32x4*)(deg + i) = (i32x4)0;
        return;
    }
    int idx = blockIdx.x * 256 + threadIdx.x;   // fid*512 + (rb*2+s)*64 + l
    if (idx >= 9 * 512) return;
    int l = idx & 63, s = (idx >> 6) & 1, rb = (idx >> 7) & 3, fid = idx >> 9;
    const float* Wt[7] = {P2, A1, A2, Wout, Wout, Win, Wlin};
    bool lo = (fid == 4);
#pragma unroll
    for (int b = 0; b < 8; ++b) {
        int in = 32 * s + 8 * (l >> 4) + b;
        int out = 16 * rb + (l & 15);
        float w;
        if (fid >= 7) {
            const float* Wsel = (fid == 7) ? Wdst : Wsrc;
            float acc = 0.f;
            for (int k = 0; k < 64; ++k) acc += Wsel[in * 64 + k] * A1[k * 64 + out];
            w = acc;
        } else {
            w = Wt[fid][in * 64 + out];
            if (fid == 2) w *= 1.44269504088896f;   // fold exp->exp2
        }
        short hi = f2bf(w);
        Apack[idx * 8 + b] = lo ? f2bf(w - bf2f((unsigned short)hi)) : hi;
    }
}

#define MFMA(a, b, c) __builtin_amdgcn_mfma_f32_16x16x32_bf16(a, b, c, 0, 0, 0)

// ---- fused front: node MFMA (768, grid-stride) || hist+slot (4096) || srtj zero (2048)
// gsv row (192 bf16): [0..63]=q ; [64+32rb+8g+0..3]=s ; [64+32rb+8g+4..7]=v
__global__ void __launch_bounds__(256) k_front(
    const float* __restrict__ x, const float* __restrict__ pos,
    const short* __restrict__ Apack,
    const float* __restrict__ bin, const float* __restrict__ a1,
    const float* __restrict__ P1, const float* __restrict__ p1,
    const int* __restrict__ ei, int* __restrict__ deg, int* __restrict__ eslot,
    int* __restrict__ srtj,
    unsigned short* __restrict__ gsv, unsigned short* __restrict__ nad) {
    if (blockIdx.x >= 4864) {          // srtj zeroing: 2048 blocks x 256 x 4 ints
        int i = (blockIdx.x - 4864) * 1024 + threadIdx.x * 4;
        *(i32x4*)(srtj + i) = (i32x4)0;
        return;
    }
    if (blockIdx.x >= 768) {           // histogram + slot record
        int e = (blockIdx.x - 768) * 256 + threadIdx.x;
        eslot[e] = atomicAdd(&deg[ei[NE + e]], 1);
        return;
    }
    __shared__ short AW2[4 * 4096];   // fids 5..8: Win, Wlin, Wda, Wsa
    __shared__ float cb[384];         // [0]bin [64]a1 [128]p1 [192..384]P1
    __shared__ unsigned stg[4][768];  // per-wave transpose stage: 64 lanes x 12 words
    {
        const int* gA = (const int*)(Apack + 5 * 4096);
        int* sA = (int*)AW2;
        for (int i = threadIdx.x; i < 8192; i += 256) sA[i] = gA[i];
        if (threadIdx.x < 64) {
            cb[threadIdx.x] = bin[threadIdx.x];
            cb[64 + threadIdx.x] = a1[threadIdx.x];
            cb[128 + threadIdx.x] = p1[threadIdx.x];
        }
        if (threadIdx.x < 192) cb[192 + threadIdx.x] = P1[threadIdx.x];
    }
    __syncthreads();
    int l = threadIdx.x & 63, g = l >> 4, e = l & 15;
    // destination-centric transpose stage addressing (stride 12 words = 48B)
    unsigned* sbw = stg[threadIdx.x >> 6];
    int wbase = (l & 16) ? 2 : 0;
    int tdst1 = 16 * ((l >= 32) ? 1 : 0) + e;
    unsigned* wp0 = sbw + tdst1 * 12 + wbase;
    unsigned* wp1 = wp0 + 4;
    unsigned* wp2 = sbw + (tdst1 + 32) * 12 + wbase;
    unsigned* wp3 = wp2 + 4;
    const unsigned* rp0 = sbw + l * 12;
    const unsigned* rp1 = rp0 + 4;
#define AF2(f, rb, s) (*(const short8*)(AW2 + ((((f) * 4 + (rb)) * 2 + (s)) * 64 + l) * 8))
#define XPOSE(cA, cB, f0, f1)                                              \
    {                                                                      \
        u32x2 _a; _a[0] = cA[0]; _a[1] = cA[1]; *(u32x2*)wp0 = _a;         \
        _a[0] = cB[0]; _a[1] = cB[1]; *(u32x2*)wp1 = _a;                   \
        _a[0] = cA[2]; _a[1] = cA[3]; *(u32x2*)wp2 = _a;                   \
        _a[0] = cB[2]; _a[1] = cB[3]; *(u32x2*)wp3 = _a;                   \
        f0 = __builtin_bit_cast(short8, *(const u32x4*)rp0);               \
        f1 = __builtin_bit_cast(short8, *(const u32x4*)rp1);               \
    }
    int wv = blockIdx.x * 4 + (threadIdx.x >> 6);   // 0..3071
    for (int tile = wv; tile < 4096; tile += 3072) {
        int n = tile * 16 + e;
        float p0 = pos[n * 3 + 0], p1v = pos[n * 3 + 1], p2v = pos[n * 3 + 2];
        const float* xr = x + (size_t)n * 64 + 8 * g;
        f32x4 x00 = *(const f32x4*)(xr), x01 = *(const f32x4*)(xr + 4);
        f32x4 x10 = *(const f32x4*)(xr + 32), x11 = *(const f32x4*)(xr + 36);
        short8 xh[2], xl[2];
#pragma unroll
        for (int b = 0; b < 4; ++b) {
            float f;
            f = x00[b]; xh[0][b] = f2bf(f);     xl[0][b] = f2bf(f - bf2f((unsigned short)xh[0][b]));
            f = x01[b]; xh[0][b + 4] = f2bf(f); xl[0][b + 4] = f2bf(f - bf2f((unsigned short)xh[0][b + 4]));
            f = x10[b]; xh[1][b] = f2bf(f);     xl[1][b] = f2bf(f - bf2f((unsigned short)xh[1][b]));
            f = x11[b]; xh[1][b + 4] = f2bf(f); xl[1][b + 4] = f2bf(f - bf2f((unsigned short)xh[1][b + 4]));
        }
        // h = relu(Win^T x + bin)
        f32x4 acc[4];
#pragma unroll
        for (int rb = 0; rb < 4; ++rb) acc[rb] = *(const f32x4*)(cb + 16 * rb + 4 * g);
#pragma unroll
        for (int rb = 0; rb < 4; ++rb) {
            acc[rb] = MFMA(AF2(0, rb, 0), xh[0], acc[rb]);
            acc[rb] = MFMA(AF2(0, rb, 1), xh[1], acc[rb]);
            acc[rb] = MFMA(AF2(0, rb, 0), xl[0], acc[rb]);
            acc[rb] = MFMA(AF2(0, rb, 1), xl[1], acc[rb]);
        }
        f32x4 hv[4], res[4];
#pragma unroll
        for (int rb = 0; rb < 4; ++rb)
#pragma unroll
            for (int c = 0; c < 4; ++c) {
                float f = frelu(acc[rb][c]);
                hv[rb][c] = f;
                res[rb][c] = f - bf2f((unsigned short)f2bf(f));
            }
        u32x4 HhA, HhB, HlA, HlB;
        HhA[0] = pk2(hv[0][0], hv[0][1]); HhA[1] = pk2(hv[0][2], hv[0][3]);
        HhA[2] = pk2(hv[1][0], hv[1][1]); HhA[3] = pk2(hv[1][2], hv[1][3]);
        HhB[0] = pk2(hv[2][0], hv[2][1]); HhB[1] = pk2(hv[2][2], hv[2][3]);
        HhB[2] = pk2(hv[3][0], hv[3][1]); HhB[3] = pk2(hv[3][2], hv[3][3]);
        HlA[0] = pk2(res[0][0], res[0][1]); HlA[1] = pk2(res[0][2], res[0][3]);
        HlA[2] = pk2(res[1][0], res[1][1]); HlA[3] = pk2(res[1][2], res[1][3]);
        HlB[0] = pk2(res[2][0], res[2][1]); HlB[1] = pk2(res[2][2], res[2][3]);
        HlB[2] = pk2(res[3][0], res[3][1]); HlB[3] = pk2(res[3][2], res[3][3]);
        short8 bhh0, bhh1, bhl0, bhl1;
        XPOSE(HhA, HhB, bhh0, bhh1);
        XPOSE(HlA, HlB, bhl0, bhl1);

        unsigned short* gr = gsv + (size_t)n * 192;
        unsigned short* nr = nad + (size_t)n * 128;
        f32x4 vres[4];
#pragma unroll
        for (int rb = 0; rb < 4; ++rb) {   // v = h @ Wlin (regs)
            f32x4 a = (f32x4)0.f;
            a = MFMA(AF2(1, rb, 0), bhh0, a);
            a = MFMA(AF2(1, rb, 1), bhh1, a);
            a = MFMA(AF2(1, rb, 0), bhl0, a);
            a = MFMA(AF2(1, rb, 1), bhl1, a);
            vres[rb] = a;
        }
#pragma unroll
        for (int rb = 0; rb < 4; ++rb) {   // s = h @ Wsa; write combined {s,v} b128
            f32x4 a = (f32x4)0.f;
            a = MFMA(AF2(3, rb, 0), bhh0, a);
            a = MFMA(AF2(3, rb, 1), bhh1, a);
            a = MFMA(AF2(3, rb, 0), bhl0, a);
            a = MFMA(AF2(3, rb, 1), bhl1, a);
            u32x4 wv4;
            wv4[0] = pk2(a[0], a[1]); wv4[1] = pk2(a[2], a[3]);
            wv4[2] = pk2(vres[rb][0], vres[rb][1]); wv4[3] = pk2(vres[rb][2], vres[rb][3]);
            *(u32x4*)(gr + 64 + 32 * rb + 8 * g) = wv4;
        }
#pragma unroll
        for (int rb = 0; rb < 4; ++rb) {   // ad = h @ Wda + a1
            f32x4 a = *(const f32x4*)(cb + 64 + 16 * rb + 4 * g);
            a = MFMA(AF2(2, rb, 0), bhh0, a);
            a = MFMA(AF2(2, rb, 1), bhh1, a);
            a = MFMA(AF2(2, rb, 0), bhl0, a);
            a = MFMA(AF2(2, rb, 1), bhl1, a);
            st4(nr + 64 + 16 * rb + 4 * g, a);
        }
#pragma unroll
        for (int rb = 0; rb < 4; ++rb) {   // q = pos @ P1 ; qp = q + p1
            f32x4 qv, qpv;
#pragma unroll
            for (int c = 0; c < 4; ++c) {
                int ch = 16 * rb + 4 * g + c;
                float q = p0 * cb[192 + ch] + p1v * cb[256 + ch] + p2v * cb[320 + ch];
                qv[c] = q; qpv[c] = q + cb[128 + ch];
            }
            st4(gr + 16 * rb + 4 * g, qv);
            st4(nr + 16 * rb + 4 * g, qpv);
        }
    }
#undef AF2
#undef XPOSE
}

// pure scan (wstart computed in k_edge; vectorized int4 loads/stores)
__global__ void __launch_bounds__(1024) k_scan(const int* __restrict__ deg,
                                               int* __restrict__ poff) {
    __shared__ int part[1024];
    int t = threadIdx.x;
    int base = t * 64;
    int s = 0;
#pragma unroll
    for (int r = 0; r < 64; r += 4) {
        i32x4 d = *(const i32x4*)(deg + base + r);
        s += ((d[0] + 15) & ~15) + ((d[1] + 15) & ~15)
           + ((d[2] + 15) & ~15) + ((d[3] + 15) & ~15);
    }
    part[t] = s;
    __syncthreads();
    int v = s;
    for (int off = 1; off < 1024; off <<= 1) {
        int add = (t >= off) ? part[t - off] : 0;
        __syncthreads();
        v += add; part[t] = v;
        __syncthreads();
    }
    int run = v - s;   // exclusive prefix
#pragma unroll
    for (int r = 0; r < 64; r += 4) {
        i32x4 d = *(const i32x4*)(deg + base + r);
        i32x4 po;
#pragma unroll
        for (int k = 0; k < 4; ++k) { po[k] = run; run += (d[k] + 15) & ~15; }
        *(i32x4*)(poff + base + r) = po;
    }
    if (t == 1023) poff[NN] = run;
}

// ---- atomic-free scatter using recorded slots ----
__global__ void k_scatter(const int* __restrict__ ei, const int* __restrict__ eslot,
                          const int* __restrict__ poff, int* __restrict__ srtj) {
    int e = blockIdx.x * 256 + threadIdx.x;
    int i = ei[NE + e];
    srtj[poff[i] + eslot[e]] = ei[e] * 192;   // pre-scaled element offset into gsv
}

// ---- persistent fused edge MLP; self-partition, LDS transpose, prefetch rotation ----
__global__ void __launch_bounds__(256) k_edge(
    const unsigned short* __restrict__ gsv, const unsigned short* __restrict__ nad,
    const int* __restrict__ poff, const int* __restrict__ deg,
    const int* __restrict__ srtj, const short* __restrict__ Apack,
    const float* __restrict__ p2b, const float* __restrict__ a2b,
    unsigned short* __restrict__ obf) {
    __shared__ short AwLds[12288];     // 3 layers x 4 rb x 2 s x 64 lanes x 8 bf16
    __shared__ float biasLds[128];     // [0]p2b [64]a2b(x log2e)
    __shared__ unsigned stg[4][768];   // per-wave transpose stage: 64 lanes x 12 words
    {
        const int* gA = (const int*)Apack;
        int* sA = (int*)AwLds;
        for (int i = threadIdx.x; i < 6144; i += 256) sA[i] = gA[i];
        if (threadIdx.x < 64) {
            biasLds[threadIdx.x] = p2b[threadIdx.x];
            biasLds[64 + threadIdx.x] = a2b[threadIdx.x] * 1.44269504088896f;
        }
    }

    int l = threadIdx.x & 63;
    int g = l >> 4, e = l & 15;
    int w = blockIdx.x * 4 + (threadIdx.x >> 6);   // 0..EW-1

    // self-computed tile-balanced partition (overlaps with LDS staging above)
    int tot = poff[NN];
    int node, nodeEnd;
    {
        long long t1l = (long long)w * tot;
        int tgt = (int)(t1l / EW);
        int lo = 0, hi2 = NN;
        while (lo < hi2) { int mid = (lo + hi2) >> 1; if (poff[mid] < tgt) lo = mid + 1; else hi2 = mid; }
        node = lo;
        if (w + 1 == EW) nodeEnd = NN;
        else {
            int tgt2 = (int)((t1l + tot) / EW);
            lo = 0; hi2 = NN;
            while (lo < hi2) { int mid = (lo + hi2) >> 1; if (poff[mid] < tgt2) lo = mid + 1; else hi2 = mid; }
            nodeEnd = lo;
        }
    }
    __syncthreads();

    // destination-centric transpose stage addressing (stride 12 words = 48B)
    unsigned* sbw = stg[threadIdx.x >> 6];
    int wbase = (l & 16) ? 2 : 0;
    int tdst1 = 16 * ((l >= 32) ? 1 : 0) + e;
    unsigned* wp0 = sbw + tdst1 * 12 + wbase;
    unsigned* wp1 = wp0 + 4;
    unsigned* wp2 = sbw + (tdst1 + 32) * 12 + wbase;
    unsigned* wp3 = wp2 + 4;
    const unsigned* rp0 = sbw + l * 12;
    const unsigned* rp1 = rp0 + 4;

#define AW(L, rb, s) (*(const short8*)(AwLds + ((((L) * 4 + (rb)) * 2 + (s)) * 64 + l) * 8))
#define XPOSE(cA, cB, f0, f1)                                              \
    {                                                                      \
        u32x2 _a; _a[0] = cA[0]; _a[1] = cA[1]; *(u32x2*)wp0 = _a;         \
        _a[0] = cB[0]; _a[1] = cB[1]; *(u32x2*)wp1 = _a;                   \
        _a[0] = cA[2]; _a[1] = cA[3]; *(u32x2*)wp2 = _a;                   \
        _a[0] = cB[2]; _a[1] = cB[3]; *(u32x2*)wp3 = _a;                   \
        f0 = __builtin_bit_cast(short8, *(const u32x4*)rp0);               \
        f1 = __builtin_bit_cast(short8, *(const u32x4*)rp1);               \
    }

    while (node < nodeEnd && poff[node + 1] == poff[node]) {
        if (e == 0) {
            unsigned short* op = obf + (size_t)node * 64;
#pragma unroll
            for (int rb = 0; rb < 4; ++rb) *(u32x2*)(op + 16 * rb + 4 * g) = (u32x2)0u;
        }
        ++node;
    }
    if (node >= nodeEnd) return;

    int t0 = poff[node], t1 = poff[node + 1];
    int vend = t0 + deg[node];
    int tendW = poff[nodeEnd];

    // current node constants: qp and adv pre-unpacked to f32 (per-node, not per-tile)
    f32x4 qpfA[2], qpfB[2];
    f32x4 advf[4];
    {
        const unsigned short* nr = nad + (size_t)node * 128;
        bf16x8 qa = *(const bf16x8*)(nr + 8 * g);
        bf16x8 qb = *(const bf16x8*)(nr + 32 + 8 * g);
#pragma unroll
        for (int k = 0; k < 8; ++k) {
            qpfA[k >> 2][k & 3] = bf2f(qa[k]);
            qpfB[k >> 2][k & 3] = bf2f(qb[k]);
        }
#pragma unroll
        for (int rb = 0; rb < 4; ++rb) {
            bf16x4 a = *(const bf16x4*)(nr + 64 + 16 * rb + 4 * g);
#pragma unroll
            for (int c = 0; c < 4; ++c) advf[rb][c] = bf2f(a[c]);
        }
    }

    // next-node prefetch state (kept packed)
    int prefN = (node + 1 < NN) ? node + 1 : NN - 1;
    const unsigned short* pr = nad + (size_t)prefN * 128;
    bf16x8 pqpA = *(const bf16x8*)(pr + 8 * g);
    bf16x8 pqpB = *(const bf16x8*)(pr + 32 + 8 * g);
    bf16x4 padv[4];
#pragma unroll
    for (int rb = 0; rb < 4; ++rb)
        padv[rb] = *(const bf16x4*)(pr + 64 + 16 * rb + 4 * g);
    int pt1 = poff[prefN + 1];
    int pdeg = deg[prefN];

    f32x4 num[4], den[4];
#pragma unroll
    for (int rb = 0; rb < 4; ++rb) { num[rb] = (f32x4)0.f; den[rb] = (f32x4)0.f; }

    // edge pipeline prologue
    int j1 = srtj[t0 + 16 + e];
    const unsigned short* g0 = gsv + srtj[t0 + e];
    bf16x8 q0A = *(const bf16x8*)(g0 + 8 * g);
    bf16x8 q0B = *(const bf16x8*)(g0 + 32 + 8 * g);
    bf16x8 svld[4];   // [0..3]=s, [4..7]=v per rb
#pragma unroll
    for (int rb = 0; rb < 4; ++rb)
        svld[rb] = *(const bf16x8*)(g0 + 64 + 32 * rb + 8 * g);

    for (int tb = t0; tb < tendW; tb += 16) {
        int j2 = srtj[tb + 32 + e];                      // 2-ahead (sequential)
        const unsigned short* g1 = gsv + j1;             // 1-ahead gather
        bf16x8 nqA = *(const bf16x8*)(g1 + 8 * g);
        bf16x8 nqB = *(const bf16x8*)(g1 + 32 + 8 * g);

        // u = lrelu(qp_i - q_j) -> bf16 B-frags (qp already f32)
        u32x4 buA, buB;
#pragma unroll
        for (int p = 0; p < 4; ++p) {
            float u0 = lrelu(qpfA[p >> 1][(2 * p) & 3] - bf2f(q0A[2 * p]));
            float u1 = lrelu(qpfA[p >> 1][(2 * p + 1) & 3] - bf2f(q0A[2 * p + 1]));
            buA[p] = pk2(u0, u1);
            u0 = lrelu(qpfB[p >> 1][(2 * p) & 3] - bf2f(q0B[2 * p]));
            u1 = lrelu(qpfB[p >> 1][(2 * p + 1) & 3] - bf2f(q0B[2 * p + 1]));
            buB[p] = pk2(u0, u1);
        }
        short8 bu0 = __builtin_bit_cast(short8, buA);
        short8 bu1 = __builtin_bit_cast(short8, buB);

        // layer 1: d^T = P2^T u^T + p2b
        f32x4 acc[4];
#pragma unroll
        for (int rb = 0; rb < 4; ++rb) acc[rb] = *(const f32x4*)(biasLds + 16 * rb + 4 * g);
#pragma unroll
        for (int rb = 0; rb < 4; ++rb) {
            acc[rb] = MFMA(AW(0, rb, 0), bu0, acc[rb]);
            acc[rb] = MFMA(AW(0, rb, 1), bu1, acc[rb]);
        }
        f32x4 d4[4];
#pragma unroll
        for (int rb = 0; rb < 4; ++rb)
#pragma unroll
            for (int c = 0; c < 4; ++c) d4[rb][c] = lrelu(acc[rb][c]);
        u32x4 dA, dB;
        dA[0] = pk2(d4[0][0], d4[0][1]); dA[1] = pk2(d4[0][2], d4[0][3]);
        dA[2] = pk2(d4[1][0], d4[1][1]); dA[3] = pk2(d4[1][2], d4[1][3]);
        dB[0] = pk2(d4[2][0], d4[2][1]); dB[1] = pk2(d4[2][2], d4[2][3]);
        dB[2] = pk2(d4[3][0], d4[3][1]); dB[3] = pk2(d4[3][2], d4[3][3]);
        short8 bd0, bd1;
        XPOSE(dA, dB, bd0, bd1);

        // layer 2 init: adv_i - as1_j (s = svld[rb][0..3])
#pragma unroll
        for (int rb = 0; rb < 4; ++rb) {
            f32x4 t;
#pragma unroll
            for (int c = 0; c < 4; ++c) t[c] = advf[rb][c] - bf2f(svld[rb][c]);
            acc[rb] = t;
        }
#pragma unroll
        for (int rb = 0; rb < 4; ++rb) {
            acc[rb] = MFMA(AW(1, rb, 0), bd0, acc[rb]);
            acc[rb] = MFMA(AW(1, rb, 1), bd1, acc[rb]);
        }
        u32x4 tA, tB;
        tA[0] = pk2(frelu(acc[0][0]), frelu(acc[0][1]));
        tA[1] = pk2(frelu(acc[0][2]), frelu(acc[0][3]));
        tA[2] = pk2(frelu(acc[1][0]), frelu(acc[1][1]));
        tA[3] = pk2(frelu(acc[1][2]), frelu(acc[1][3]));
        tB[0] = pk2(frelu(acc[2][0]), frelu(acc[2][1]));
        tB[1] = pk2(frelu(acc[2][2]), frelu(acc[2][3]));
        tB[2] = pk2(frelu(acc[3][0]), frelu(acc[3][1]));
        tB[3] = pk2(frelu(acc[3][2]), frelu(acc[3][3]));
        short8 bt0, bt1;
        XPOSE(tA, tB, bt0, bt1);

        // layer 3: alpha2^T = (A2 log2e)^T t^T + a2 log2e
#pragma unroll
        for (int rb = 0; rb < 4; ++rb) acc[rb] = *(const f32x4*)(biasLds + 64 + 16 * rb + 4 * g);
#pragma unroll
        for (int rb = 0; rb < 4; ++rb) {
            acc[rb] = MFMA(AW(2, rb, 0), bt0, acc[rb]);
            acc[rb] = MFMA(AW(2, rb, 1), bt1, acc[rb]);
        }

        // softmax accumulate: exp(relu(alpha)) = exp2(relu(alpha*log2e))
        bool ok = (tb + e) < vend;
#pragma unroll
        for (int rb = 0; rb < 4; ++rb) {
#pragma unroll
            for (int c = 0; c < 4; ++c) {
                float a = frelu(acc[rb][c]);
                float ew = ok ? exp2f(a) : 0.f;
                den[rb][c] += ew;
                num[rb][c] += ew * (bf2f(svld[rb][4 + c]) + d4[rb][c]);
            }
        }
        // svld dead -> next tile's combined {s,v} gather (4 b128)
#pragma unroll
        for (int rb = 0; rb < 4; ++rb)
            svld[rb] = *(const bf16x8*)(g1 + 64 + 32 * rb + 8 * g);

        q0A = nqA; q0B = nqB; j1 = j2;

        // node epilogue
        if (tb + 16 >= t1) {
            // reduce over 16 edge-lanes: xor1/xor2 via DPP (VALU), xor4/xor8 via shfl (DS)
#pragma unroll
            for (int rb = 0; rb < 4; ++rb)
#pragma unroll
                for (int c = 0; c < 4; ++c) {
                    float n2 = dppadd<0xB1>(num[rb][c]);   // + lane^1 (quad_perm 1,0,3,2)
                    float d2 = dppadd<0xB1>(den[rb][c]);
                    n2 = dppadd<0x4E>(n2);                 // + lane^2 (quad_perm 2,3,0,1)
                    d2 = dppadd<0x4E>(d2);
                    n2 += __shfl_xor(n2, 4);
                    d2 += __shfl_xor(d2, 4);
                    n2 += __shfl_xor(n2, 8);
                    d2 += __shfl_xor(d2, 8);
                    num[rb][c] = n2; den[rb][c] = d2;
                }
            if (e == 0) {
                unsigned short* op = obf + (size_t)node * 64;
#pragma unroll
                for (int rb = 0; rb < 4; ++rb) {
                    f32x4 ov;
#pragma unroll
                    for (int c = 0; c < 4; ++c)
                        ov[c] = num[rb][c] * __builtin_amdgcn_rcpf(den[rb][c] + 1e-16f);
                    u32x2 ow; ow[0] = pk2(ov[0], ov[1]); ow[1] = pk2(ov[2], ov[3]);
                    *(u32x2*)(op + 16 * rb + 4 * g) = ow;
                }
            }
            ++node;
            if (node < nodeEnd && node == prefN && pt1 != t1) {
                t0 = t1; t1 = pt1; vend = t0 + pdeg;
#pragma unroll
                for (int k = 0; k < 8; ++k) {
                    qpfA[k >> 2][k & 3] = bf2f(pqpA[k]);
                    qpfB[k >> 2][k & 3] = bf2f(pqpB[k]);
                }
#pragma unroll
                for (int rb = 0; rb < 4; ++rb)
#pragma unroll
                    for (int c = 0; c < 4; ++c) advf[rb][c] = bf2f(padv[rb][c]);
            } else {
                while (node < nodeEnd && poff[node + 1] == t1) {
                    if (e == 0) {
                        unsigned short* op = obf + (size_t)node * 64;
#pragma unroll
                        for (int rb = 0; rb < 4; ++rb)
                            *(u32x2*)(op + 16 * rb + 4 * g) = (u32x2)0u;
                    }
                    ++node;
                }
                if (node < nodeEnd) {
                    t0 = t1; t1 = poff[node + 1];
                    vend = t0 + deg[node];
                    const unsigned short* nr2 = nad + (size_t)node * 128;
                    bf16x8 qa = *(const bf16x8*)(nr2 + 8 * g);
                    bf16x8 qb = *(const bf16x8*)(nr2 + 32 + 8 * g);
#pragma unroll
                    for (int k = 0; k < 8; ++k) {
                        qpfA[k >> 2][k & 3] = bf2f(qa[k]);
                        qpfB[k >> 2][k & 3] = bf2f(qb[k]);
                    }
#pragma unroll
                    for (int rb = 0; rb < 4; ++rb) {
                        bf16x4 a = *(const bf16x4*)(nr2 + 64 + 16 * rb + 4 * g);
#pragma unroll
                        for (int c = 0; c < 4; ++c) advf[rb][c] = bf2f(a[c]);
                    }
                }
            }
            if (node < nodeEnd) {
                prefN = (node + 1 < NN) ? node + 1 : NN - 1;
                const unsigned short* pr2 = nad + (size_t)prefN * 128;
                pqpA = *(const bf16x8*)(pr2 + 8 * g);
                pqpB = *(const bf16x8*)(pr2 + 32 + 8 * g);
#pragma unroll
                for (int rb = 0; rb < 4; ++rb)
                    padv[rb] = *(const bf16x4*)(pr2 + 64 + 16 * rb + 4 * g);
                pt1 = poff[prefN + 1];
                pdeg = deg[prefN];
#pragma unroll
                for (int rb = 0; rb < 4; ++rb) { num[rb] = (f32x4)0.f; den[rb] = (f32x4)0.f; }
            }
        }
    }
#undef AW
#undef XPOSE
}

// ---- out = relu(o @ Wout + bout); o read directly as bf16 B-frags ----
__global__ void __launch_bounds__(512) k_out(const unsigned short* __restrict__ obf,
                                             const short* __restrict__ Apack,
                                             const float* __restrict__ bout,
                                             float* __restrict__ out) {
    __shared__ short Ah[4096], Al[4096];
    __shared__ float bb[64];
    {
        const int* gh = (const int*)(Apack + 3 * 4096);
        const int* gl = (const int*)(Apack + 4 * 4096);
        int* sh = (int*)Ah; int* sl = (int*)Al;
        for (int i = threadIdx.x; i < 2048; i += 512) { sh[i] = gh[i]; sl[i] = gl[i]; }
        if (threadIdx.x < 64) bb[threadIdx.x] = bout[threadIdx.x];
    }
    __syncthreads();
    int l = threadIdx.x & 63, g = l >> 4;
    int tile = blockIdx.x * 8 + (threadIdx.x >> 6);   // 0..4095
    int nbase = tile * 16;
    const unsigned short* op = obf + (size_t)(nbase + (l & 15)) * 64;
    short8 b0 = __builtin_bit_cast(short8, *(const bf16x8*)(op + 8 * g));
    short8 b1 = __builtin_bit_cast(short8, *(const bf16x8*)(op + 32 + 8 * g));
#define AF(arr, rb, s) (*(const short8*)(arr + (((rb) * 2 + (s)) * 64 + l) * 8))
    f32x4 acc[4];
#pragma unroll
    for (int rb = 0; rb < 4; ++rb) acc[rb] = *(const f32x4*)(bb + 16 * rb + 4 * g);
#pragma unroll
    for (int rb = 0; rb < 4; ++rb) {
        acc[rb] = MFMA(AF(Ah, rb, 0), b0, acc[rb]);
        acc[rb] = MFMA(AF(Ah, rb, 1), b1, acc[rb]);
        acc[rb] = MFMA(AF(Al, rb, 0), b0, acc[rb]);
        acc[rb] = MFMA(AF(Al, rb, 1), b1, acc[rb]);
    }
#undef AF
    float* outp = out + (size_t)(nbase + (l & 15)) * 64;
#pragma unroll
    for (int rb = 0; rb < 4; ++rb) {
        f32x4 r;
#pragma unroll
        for (int c = 0; c < 4; ++c) r[c] = frelu(acc[rb][c]);
        *(f32x4*)(outp + 16 * rb + 4 * g) = r;
    }
}

extern "C" void kernel_launch(void* const* d_in, const int* in_sizes, int n_in,
                              void* d_out, int out_size, void* d_ws, size_t ws_size,
                              hipStream_t stream) {
    const float* x    = (const float*)d_in[0];
    const float* pos  = (const float*)d_in[1];
    const int*   ei   = (const int*)d_in[2];
    const float* Win  = (const float*)d_in[3];
    const float* bin  = (const float*)d_in[4];
    const float* Wout = (const float*)d_in[5];
    const float* bout = (const float*)d_in[6];
    const float* Wlin = (const float*)d_in[7];
    const float* Wsrc = (const float*)d_in[8];
    const float* Wdst = (const float*)d_in[9];
    const float* P1   = (const float*)d_in[10];
    const float* p1   = (const float*)d_in[11];
    const float* P2   = (const float*)d_in[12];
    const float* p2   = (const float*)d_in[13];
    const float* A1   = (const float*)d_in[14];
    const float* a1   = (const float*)d_in[15];
    const float* A2   = (const float*)d_in[16];
    const float* a2   = (const float*)d_in[17];
    float* out = (float*)d_out;

    char* w = (char*)d_ws;
    short* Apck = (short*)w; w += 9 * 4096 * 2;
    unsigned short* obf = (unsigned short*)w; w += (size_t)NN * 64 * 2;
    unsigned short* gsv = (unsigned short*)w; w += (size_t)NN * 192 * 2;
    unsigned short* nad = (unsigned short*)w; w += (size_t)NN * 128 * 2;
    int* deg    = (int*)w; w += (size_t)NN * 4;
    int* poffp  = (int*)w; w += (size_t)(NN + 16) * 4;
    int* eslot  = (int*)w; w += (size_t)NE * 4;
    int* srtj   = (int*)w; w += (size_t)2 * NE * 4;

    k_pack<<<18 + 64, 256, 0, stream>>>(P2, A1, A2, Wout, Win, Wlin, Wdst, Wsrc,
                                        Apck, deg);
    k_front<<<768 + 4096 + 2048, 256, 0, stream>>>(x, pos, Apck, bin, a1, P1, p1,
                                                   ei, deg, eslot, srtj, gsv, nad);
    k_scan<<<1, 1024, 0, stream>>>(deg, poffp);
    k_scatter<<<NE / 256, 256, 0, stream>>>(ei, eslot, poffp, srtj);
    k_edge<<<EW / 4, 256, 0, stream>>>(gsv, nad, poffp, deg, srtj, Apck,
                                       p2, a2, obf);
    k_out<<<512, 512, 0, stream>>>(obf, Apck, bout, out);
}